// Round 8
// baseline (185.262 us; speedup 1.0000x reference)
//
#include <hip/hip_runtime.h>
#include <math.h>

#define B_ 4
#define N_ 8192
#define C_ 512
#define H_ 8
#define M_ (B_ * N_) /* 32768 */

typedef __attribute__((ext_vector_type(8))) short bf16x8;
typedef __attribute__((ext_vector_type(4))) float f32x4;
typedef __attribute__((ext_vector_type(8))) unsigned short u16x8;
typedef __attribute__((ext_vector_type(4))) unsigned short u16x4;

__device__ __forceinline__ float b2f(unsigned short u) {
  union { unsigned int i; float f; } v;
  v.i = ((unsigned int)u) << 16;
  return v.f;
}
__device__ __forceinline__ unsigned short f2b(float f) {
  union { float f; unsigned int i; } v;
  v.f = f;
  unsigned int r = v.i + 0x7fff + ((v.i >> 16) & 1);
  return (unsigned short)(r >> 16);
}
__device__ __forceinline__ void gl_lds16(const void* g, void* l) {
  __builtin_amdgcn_global_load_lds(
      (const __attribute__((address_space(1))) unsigned int*)g,
      (__attribute__((address_space(3))) unsigned int*)l, 16, 0, 0);
}

// ---------------------------------------------------------------------------
// K1: LayerNorm over C=512 -> bf16. One wave per row.
// ---------------------------------------------------------------------------
__global__ __launch_bounds__(256) void ln_bf16(
    const float* __restrict__ x, const float* __restrict__ gam,
    const float* __restrict__ bet, unsigned short* __restrict__ y) {
  int wave = threadIdx.x >> 6, lane = threadIdx.x & 63;
  int row = (blockIdx.x << 2) + wave;
  const float4* xr = (const float4*)(x + (size_t)row * C_);
  float4 v0 = xr[lane], v1 = xr[lane + 64];
  float s = v0.x + v0.y + v0.z + v0.w + v1.x + v1.y + v1.z + v1.w;
  float q = v0.x * v0.x + v0.y * v0.y + v0.z * v0.z + v0.w * v0.w +
            v1.x * v1.x + v1.y * v1.y + v1.z * v1.z + v1.w * v1.w;
#pragma unroll
  for (int off = 32; off; off >>= 1) {
    s += __shfl_xor(s, off);
    q += __shfl_xor(q, off);
  }
  float mean = s * (1.0f / C_);
  float var = q * (1.0f / C_) - mean * mean;
  float rstd = rsqrtf(var + 1e-5f);
  const float4* gr = (const float4*)gam;
  const float4* br = (const float4*)bet;
  float4 g0 = gr[lane], g1 = gr[lane + 64];
  float4 b0 = br[lane], b1 = br[lane + 64];
  u16x4 oa, ob;
  oa.x = f2b((v0.x - mean) * rstd * g0.x + b0.x);
  oa.y = f2b((v0.y - mean) * rstd * g0.y + b0.y);
  oa.z = f2b((v0.z - mean) * rstd * g0.z + b0.z);
  oa.w = f2b((v0.w - mean) * rstd * g0.w + b0.w);
  ob.x = f2b((v1.x - mean) * rstd * g1.x + b1.x);
  ob.y = f2b((v1.y - mean) * rstd * g1.y + b1.y);
  ob.z = f2b((v1.z - mean) * rstd * g1.z + b1.z);
  ob.w = f2b((v1.w - mean) * rstd * g1.w + b1.w);
  unsigned short* yr = y + (size_t)row * C_;
  *(u16x4*)(yr + (lane << 2)) = oa;
  *(u16x4*)(yr + 256 + (lane << 2)) = ob;
}

// ---------------------------------------------------------------------------
// K2: merged prep (weight transposes + frag precomputes).
// ---------------------------------------------------------------------------
__global__ __launch_bounds__(256) void prep_all(
    const float* __restrict__ Wx, const float* __restrict__ Wfx,
    const float* __restrict__ Wout, const float* __restrict__ Wsl,
    const float* __restrict__ Wq, const float* __restrict__ Wk,
    const float* __restrict__ Wv, const float* __restrict__ Wm1,
    const float* __restrict__ Wm2, unsigned short* __restrict__ WtX,
    unsigned short* __restrict__ WtF, unsigned short* __restrict__ WtO,
    unsigned short* __restrict__ wsf, unsigned short* __restrict__ wfr) {
  __shared__ float tile[64][65];
  int blk = blockIdx.x, t = threadIdx.x;
  if (blk < 192) {
    int which = blk >> 6, sub = blk & 63;
    const float* W = (which == 0) ? Wx : (which == 1) ? Wfx : Wout;
    unsigned short* Wt = (which == 0) ? WtX : (which == 1) ? WtF : WtO;
    int r0 = (sub >> 3) << 6, c0 = (sub & 7) << 6;
    int lr = t >> 4, lc = (t & 15) << 2;
#pragma unroll
    for (int p = 0; p < 4; p++) {
      float4 v = *(const float4*)(W + (size_t)(r0 + lr + p * 16) * 512 + c0 + lc);
      tile[lr + p * 16][lc + 0] = v.x;
      tile[lr + p * 16][lc + 1] = v.y;
      tile[lr + p * 16][lc + 2] = v.z;
      tile[lr + p * 16][lc + 3] = v.w;
    }
    __syncthreads();
    int on = t >> 2, ok = (t & 3) << 4;
    unsigned short tmp[16];
#pragma unroll
    for (int j = 0; j < 16; j++) tmp[j] = f2b(tile[ok + j][on]);
    unsigned short* op = Wt + (size_t)(c0 + on) * 512 + r0 + ok;
#pragma unroll
    for (int j4 = 0; j4 < 4; j4++)
      *(u16x4*)(op + (j4 << 2)) = *(u16x4*)(tmp + (j4 << 2));
  } else {
#pragma unroll
    for (int i = 0; i < 2; i++) {
      int idx = t + i * 256;
      int f = idx >> 6, l = idx & 63;
      int gt = f >> 1, ks = f & 1;
      int g = (gt << 4) + (l & 15);
      int d0 = (ks << 5) + ((l >> 4) << 3);
      unsigned short v[8];
#pragma unroll
      for (int jj = 0; jj < 8; jj++) v[jj] = f2b(Wsl[(size_t)(d0 + jj) * 64 + g]);
      *(u16x4*)(wsf + idx * 8) = *(u16x4*)v;
      *(u16x4*)(wsf + idx * 8 + 4) = *(u16x4*)(v + 4);
    }
    for (int task = t; task < 56 * 64; task += 256) {
      int fid = task >> 6, l = task & 63;
      const float* W;
      int stride, ct, ks;
      if (fid < 24) {
        W = (fid < 8) ? Wq : (fid < 16) ? Wk : Wv;
        int e = fid & 7;
        ct = e >> 1;
        ks = e & 1;
        stride = 64;
      } else if (fid < 40) {
        W = Wm1;
        int e = fid - 24;
        ct = e >> 1;
        ks = e & 1;
        stride = 128;
      } else {
        W = Wm2;
        int e = fid - 40;
        ct = e >> 2;
        ks = e & 3;
        stride = 64;
      }
      int d0 = (ks << 5) + ((l >> 4) << 3);
      int c = (ct << 4) + (l & 15);
      unsigned short v[8];
#pragma unroll
      for (int j = 0; j < 8; j++) v[j] = f2b(W[(size_t)(d0 + j) * stride + c]);
      *(u16x4*)(wfr + task * 8) = *(u16x4*)v;
      *(u16x4*)(wfr + task * 8 + 4) = *(u16x4*)(v + 4);
    }
  }
}

// ---------------------------------------------------------------------------
// K3c: precompute tokens^T A-operand fragments for deslice.
// ---------------------------------------------------------------------------
__global__ __launch_bounds__(256) void tokfrag_prep(
    const float* __restrict__ tokens, unsigned short* __restrict__ wtokf) {
  int bh = blockIdx.x, t = threadIdx.x, w = t >> 6, l = t & 63;
  const float* tp = tokens + ((size_t)bh << 12);
#pragma unroll
  for (int fid = w; fid < 8; fid += 4) {
    int mt = fid >> 1, ks = fid & 1;
    int d = (mt << 4) + (l & 15);
    int g0 = (ks << 5) + ((l >> 4) << 3);
    unsigned short v[8];
#pragma unroll
    for (int j = 0; j < 8; j++) v[j] = f2b(tp[(g0 + j) * 64 + d]);
    unsigned short* op = wtokf + (((size_t)bh << 3) + fid) * 512 + (l << 3);
    *(u16x4*)op = *(u16x4*)v;
    *(u16x4*)(op + 4) = *(u16x4*)(v + 4);
  }
}

// ---------------------------------------------------------------------------
// K4: bf16 MFMA GEMM, single-buffer, slot-swizzled LDS (2-way residual):
//   phys_slot = log_slot ^ ((row>>1)&3); staging permutes source within row.
// ---------------------------------------------------------------------------
template <int DEC, bool BIASROW, bool OUTBF, bool RES>
__global__ __launch_bounds__(256) void gemm_bf16(
    const unsigned short* __restrict__ A, const unsigned short* __restrict__ Bt,
    const float* __restrict__ bias, const unsigned short* __restrict__ resid,
    void* __restrict__ Cout, size_t ldC) {
  __shared__ unsigned short lds[8192];
  const int t = threadIdx.x;
  const int w = t >> 6, l = t & 63;
  int bid = blockIdx.x;
  int xcd = bid & 7, q = bid >> 3;
  int bm, bn;
  if (DEC == 0) {
    bm = ((xcd << 5) + (q >> 2)) << 7;
    bn = (q & 3) << 7;
  } else {
    bn = ((xcd << 5) + (q >> 2)) << 7;
    bm = (q & 3) << 7;
  }
  const int wm = (w >> 1) << 6, wn = (w & 1) << 6;
  f32x4 acc[4][4];
#pragma unroll
  for (int mt = 0; mt < 4; mt++)
#pragma unroll
    for (int nt = 0; nt < 4; nt++) acc[mt][nt] = (f32x4){0.f, 0.f, 0.f, 0.f};

  const int srow = t >> 2;
  const int scol = (((t & 3) ^ ((t >> 3) & 3)) << 3);  // swizzled source slot
  const unsigned short* gA0 = A + (size_t)(bm + srow) * 512 + scol;
  const unsigned short* gA1 = A + (size_t)(bm + 64 + srow) * 512 + scol;
  const unsigned short* gB0 = Bt + (size_t)(bn + srow) * 512 + scol;
  const unsigned short* gB1 = Bt + (size_t)(bn + 64 + srow) * 512 + scol;
  const int fr = l & 15;
  const int pslot = (((l >> 4) ^ ((l >> 1) & 3)) << 3);  // swizzled read slot

  for (int k0 = 0; k0 < 512; k0 += 32) {
    gl_lds16(gA0 + k0, lds + (w << 9));
    gl_lds16(gA1 + k0, lds + 2048 + (w << 9));
    gl_lds16(gB0 + k0, lds + 4096 + (w << 9));
    gl_lds16(gB1 + k0, lds + 6144 + (w << 9));
    __syncthreads();
    bf16x8 af[4], bfr[4];
#pragma unroll
    for (int mt = 0; mt < 4; mt++)
      af[mt] = *(const bf16x8*)&lds[(wm + mt * 16 + fr) * 32 + pslot];
#pragma unroll
    for (int nt = 0; nt < 4; nt++)
      bfr[nt] = *(const bf16x8*)&lds[4096 + (wn + nt * 16 + fr) * 32 + pslot];
#pragma unroll
    for (int mt = 0; mt < 4; mt++)
#pragma unroll
      for (int nt = 0; nt < 4; nt++)
        acc[mt][nt] = __builtin_amdgcn_mfma_f32_16x16x32_bf16(
            af[mt], bfr[nt], acc[mt][nt], 0, 0, 0);
    __syncthreads();
  }

  const int col0 = bn + wn + (l & 15);
  const int row0 = bm + wm + ((l >> 4) << 2);
#pragma unroll
  for (int mt = 0; mt < 4; mt++) {
#pragma unroll
    for (int j = 0; j < 4; j++) {
      int row = row0 + mt * 16 + j;
#pragma unroll
      for (int nt = 0; nt < 4; nt++) {
        int col = col0 + nt * 16;
        float v = acc[mt][nt][j] + (BIASROW ? bias[row] : bias[col]);
        if (RES) v += b2f(resid[(size_t)row * ldC + col]);
        if (OUTBF)
          ((unsigned short*)Cout)[(size_t)row * ldC + col] = f2b(v);
        else
          ((float*)Cout)[(size_t)row * ldC + col] = v;
      }
    }
  }
}

// ---------------------------------------------------------------------------
// K5: slice softmax via MFMA (round-5 version, separate kernel).
// Rows = (b,n,h) flat [262144][64] bf16 in/out, in place over x_mid.
// ---------------------------------------------------------------------------
__global__ __launch_bounds__(256) void slice_mfma(
    unsigned short* __restrict__ xw, const unsigned short* __restrict__ wf,
    const float* __restrict__ bslice, const float* __restrict__ temp) {
  __shared__ unsigned short xs[4096];
  int t = threadIdx.x, w = t >> 6, l = t & 63;
  int blk = blockIdx.x;
  size_t base = (size_t)blk << 12;
  {
    int srow = t >> 2;
    const unsigned short* gp = xw + base + srow * 64 + ((t & 3) << 4);
    u16x8 a = *(const u16x8*)gp;
    u16x8 b = *(const u16x8*)(gp + 8);
    int sl0 = (t & 3) << 1, swz = srow & 7;
    *(u16x8*)&xs[srow * 64 + ((sl0 ^ swz) << 3)] = a;
    *(u16x8*)&xs[srow * 64 + (((sl0 + 1) ^ swz) << 3)] = b;
  }
  bf16x8 wsf[4][2];
#pragma unroll
  for (int gt = 0; gt < 4; gt++)
#pragma unroll
    for (int ks = 0; ks < 2; ks++)
      wsf[gt][ks] = *(const bf16x8*)(wf + (((gt << 1) + ks) * 64 + l) * 8);
  __syncthreads();

  int xr = (w << 4) + (l & 15);
  f32x4 acc[4];
#pragma unroll
  for (int gt = 0; gt < 4; gt++) acc[gt] = (f32x4){0.f, 0.f, 0.f, 0.f};
#pragma unroll
  for (int ks = 0; ks < 2; ks++) {
    int slot = (ks << 2) + (l >> 4);
    bf16x8 xf = *(const bf16x8*)&xs[xr * 64 + ((slot ^ (xr & 7)) << 3)];
#pragma unroll
    for (int gt = 0; gt < 4; gt++)
      acc[gt] = __builtin_amdgcn_mfma_f32_16x16x32_bf16(wsf[gt][ks], xf,
                                                        acc[gt], 0, 0, 0);
  }

  int gxr = (blk << 6) + xr;
  float invt = 1.0f / temp[gxr & 7];
  int qq = l >> 4;
  float lg[16];
  float mx = -1e30f;
#pragma unroll
  for (int gt = 0; gt < 4; gt++)
#pragma unroll
    for (int r = 0; r < 4; r++) {
      float v = (acc[gt][r] + bslice[(gt << 4) + (qq << 2) + r]) * invt;
      lg[(gt << 2) + r] = v;
      mx = fmaxf(mx, v);
    }
  mx = fmaxf(mx, __shfl_xor(mx, 16));
  mx = fmaxf(mx, __shfl_xor(mx, 32));
  float ssum = 0.f;
#pragma unroll
  for (int i = 0; i < 16; i++) {
    lg[i] = expf(lg[i] - mx);
    ssum += lg[i];
  }
  ssum += __shfl_xor(ssum, 16);
  ssum += __shfl_xor(ssum, 32);
  float inv = 1.0f / ssum;
  __syncthreads();
#pragma unroll
  for (int gt = 0; gt < 4; gt++) {
    int slot = (gt << 1) + (qq >> 1);
    int off = ((slot ^ (xr & 7)) << 3) + ((qq & 1) << 2);
    u16x4 pk;
    pk.x = f2b(lg[(gt << 2) + 0] * inv);
    pk.y = f2b(lg[(gt << 2) + 1] * inv);
    pk.z = f2b(lg[(gt << 2) + 2] * inv);
    pk.w = f2b(lg[(gt << 2) + 3] * inv);
    *(u16x4*)&xs[xr * 64 + off] = pk;
  }
  __syncthreads();
  {
    int rr = (w << 4) + (l >> 2);
    int sl = (l & 3) << 1, swz = rr & 7;
    u16x8 o0 = *(const u16x8*)&xs[rr * 64 + ((sl ^ swz) << 3)];
    u16x8 o1 = *(const u16x8*)&xs[rr * 64 + (((sl + 1) ^ swz) << 3)];
    unsigned short* op = xw + base + rr * 64 + ((l & 3) << 4);
    *(u16x8*)op = o0;
    *(u16x8*)(op + 8) = o1;
  }
}

// ---------------------------------------------------------------------------
// K6: pool via MFMA (unchanged).
// ---------------------------------------------------------------------------
__global__ __launch_bounds__(256) void pool_mfma(
    const unsigned short* __restrict__ sw, const unsigned short* __restrict__ fxT,
    float* __restrict__ tok_part, float* __restrict__ norm_part) {
  __shared__ unsigned short wT[4096];
  int bid = blockIdx.x;
  int bh = bid >> 4, c = bid & 15;
  int b = bh >> 3, h = bh & 7;
  int t = threadIdx.x, w = t >> 6, l = t & 63;
  int n0 = c << 9;
  const int fr15 = l & 15, fs = l >> 4;
  f32x4 acc[4];
#pragma unroll
  for (int gt = 0; gt < 4; gt++) acc[gt] = (f32x4){0.f, 0.f, 0.f, 0.f};
  float nacc[4] = {0.f, 0.f, 0.f, 0.f};

  const unsigned short* fxrow =
      fxT + (size_t)(h * 64 + w * 16 + fr15) * 32768 + b * N_ + n0 + (fs << 3);

  for (int nn = 0; nn < 512; nn += 64) {
    size_t srow = ((size_t)(b * N_ + n0 + nn + l) * 8 + h) << 6;
    u16x8 a0 = *(const u16x8*)(sw + srow + w * 16);
    u16x8 a1 = *(const u16x8*)(sw + srow + w * 16 + 8);
    __syncthreads();
#pragma unroll
    for (int j = 0; j < 16; j++) {
      int g = (w << 4) + j;
      unsigned short v = (j < 8) ? (unsigned short)a0[j] : (unsigned short)a1[j - 8];
      wT[(g << 6) + (((l >> 3) ^ (g & 7)) << 3) + (l & 7)] = v;
    }
    __syncthreads();
#pragma unroll
    for (int kk = 0; kk < 2; kk++) {
      bf16x8 bfrag = *(const bf16x8*)(fxrow + nn + (kk << 5));
#pragma unroll
      for (int gt = 0; gt < 4; gt++) {
        int g = (gt << 4) + fr15;
        int slot = (kk << 2) + fs;
        bf16x8 af = *(const bf16x8*)&wT[(g << 6) + ((slot ^ (g & 7)) << 3)];
        acc[gt] = __builtin_amdgcn_mfma_f32_16x16x32_bf16(af, bfrag, acc[gt], 0, 0, 0);
        if (w == 0) {
#pragma unroll
          for (int j = 0; j < 8; j++) nacc[gt] += b2f((unsigned short)af[j]);
        }
      }
    }
  }
  float* op = tok_part + ((size_t)bid << 12);
#pragma unroll
  for (int gt = 0; gt < 4; gt++)
#pragma unroll
    for (int rr = 0; rr < 4; rr++)
      op[((gt << 4) + (fs << 2) + rr) * 64 + (w << 4) + fr15] = acc[gt][rr];
  if (w == 0) {
#pragma unroll
    for (int gt = 0; gt < 4; gt++) {
      float s = nacc[gt];
      s += __shfl_xor(s, 16);
      s += __shfl_xor(s, 32);
      if (l < 16) norm_part[(bid << 6) + (gt << 4) + l] = s;
    }
  }
}

// ---------------------------------------------------------------------------
// K6b: reduce tok_part chunks + norm_part -> normalized slice_tok fp32.
// ---------------------------------------------------------------------------
__global__ __launch_bounds__(256) void tok_reduce(
    const float* __restrict__ tok_part, const float* __restrict__ norm_part,
    float* __restrict__ stG) {
  int blk = blockIdx.x;
  int bh = blk >> 2, qq = blk & 3;
  int t = threadIdx.x;
  int e = (qq << 10) + (t << 2);
  int g = e >> 6;
  float s = 0.f;
  const float* np = norm_part + ((size_t)bh << 10);
#pragma unroll
  for (int c = 0; c < 16; c++) s += np[(c << 6) + g];
  float4 acc = make_float4(0.f, 0.f, 0.f, 0.f);
  const float* tp = tok_part + ((size_t)bh << 16) + e;
#pragma unroll
  for (int c = 0; c < 16; c++) {
    float4 v = *(const float4*)(tp + (c << 12));
    acc.x += v.x;
    acc.y += v.y;
    acc.z += v.z;
    acc.w += v.w;
  }
  float inv = 1.0f / (s + 1e-5f);
  acc.x *= inv;
  acc.y *= inv;
  acc.z *= inv;
  acc.w *= inv;
  *(float4*)(stG + ((size_t)bh << 12) + e) = acc;
}

// ---------------------------------------------------------------------------
// K7: token pipeline via MFMA (unchanged).
// ---------------------------------------------------------------------------
__device__ __forceinline__ float gelu_exact(float x) {
  return 0.5f * x * (1.0f + erff(x * 0.70710678118654752f));
}

__global__ __launch_bounds__(256) void token_mfma(
    const float* __restrict__ stG, const unsigned short* __restrict__ wfr,
    const float* __restrict__ tg, const float* __restrict__ tb,
    const float* __restrict__ bm1, const float* __restrict__ bm2,
    float* __restrict__ tokens) {
  __shared__ __align__(16) char smem[54272];
  unsigned short* stb = (unsigned short*)smem;
  float* st32 = (float*)(smem + 9216);
  unsigned short* hmld = (unsigned short*)(smem + 9216);
  unsigned short* qld = (unsigned short*)(smem + 26624);
  unsigned short* kld = (unsigned short*)(smem + 35840);
  unsigned short* vtl = (unsigned short*)(smem + 45056);

  int bh = blockIdx.x, t = threadIdx.x, w = t >> 6, l = t & 63;
  const int fr = l & 15, fq = l >> 4;

  {
    int r = t >> 2, c0 = (t & 3) << 4;
    const float* gp = stG + ((size_t)bh << 12) + r * 64 + c0;
    float4 a = *(const float4*)gp;
    float4 b = *(const float4*)(gp + 4);
    float4 c = *(const float4*)(gp + 8);
    float4 d = *(const float4*)(gp + 12);
    *(float4*)&st32[r * 68 + c0] = a;
    *(float4*)&st32[r * 68 + c0 + 4] = b;
    *(float4*)&st32[r * 68 + c0 + 8] = c;
    *(float4*)&st32[r * 68 + c0 + 12] = d;
    unsigned short tv[16];
    tv[0] = f2b(a.x); tv[1] = f2b(a.y); tv[2] = f2b(a.z); tv[3] = f2b(a.w);
    tv[4] = f2b(b.x); tv[5] = f2b(b.y); tv[6] = f2b(b.z); tv[7] = f2b(b.w);
    tv[8] = f2b(c.x); tv[9] = f2b(c.y); tv[10] = f2b(c.z); tv[11] = f2b(c.w);
    tv[12] = f2b(d.x); tv[13] = f2b(d.y); tv[14] = f2b(d.z); tv[15] = f2b(d.w);
    *(u16x8*)&stb[r * 72 + c0] = *(u16x8*)tv;
    *(u16x8*)&stb[r * 72 + c0 + 8] = *(u16x8*)(tv + 8);
  }
  __syncthreads();

  const int orow = (w << 4) + (fq << 2);

  {
    bf16x8 af[2];
#pragma unroll
    for (int ks = 0; ks < 2; ks++)
      af[ks] = *(const bf16x8*)&stb[((w << 4) + fr) * 72 + (ks << 5) + (fq << 3)];
    f32x4 aq[4], ak[4], av[4];
#pragma unroll
    for (int ct = 0; ct < 4; ct++) {
      aq[ct] = (f32x4){0.f, 0.f, 0.f, 0.f};
      ak[ct] = (f32x4){0.f, 0.f, 0.f, 0.f};
      av[ct] = (f32x4){0.f, 0.f, 0.f, 0.f};
    }
#pragma unroll
    for (int ct = 0; ct < 4; ct++)
#pragma unroll
      for (int ks = 0; ks < 2; ks++) {
        bf16x8 bq = *(const bf16x8*)&wfr[(((ct << 1) + ks) * 64 + l) * 8];
        aq[ct] = __builtin_amdgcn_mfma_f32_16x16x32_bf16(af[ks], bq, aq[ct], 0, 0, 0);
      }
#pragma unroll
    for (int ct = 0; ct < 4; ct++)
#pragma unroll
      for (int ks = 0; ks < 2; ks++) {
        bf16x8 bk = *(const bf16x8*)&wfr[((8 + (ct << 1) + ks) * 64 + l) * 8];
        ak[ct] = __builtin_amdgcn_mfma_f32_16x16x32_bf16(af[ks], bk, ak[ct], 0, 0, 0);
      }
#pragma unroll
    for (int ct = 0; ct < 4; ct++)
#pragma unroll
      for (int ks = 0; ks < 2; ks++) {
        bf16x8 bv = *(const bf16x8*)&wfr[((16 + (ct << 1) + ks) * 64 + l) * 8];
        av[ct] = __builtin_amdgcn_mfma_f32_16x16x32_bf16(af[ks], bv, av[ct], 0, 0, 0);
      }
#pragma unroll
    for (int ct = 0; ct < 4; ct++) {
#pragma unroll
      for (int rr = 0; rr < 4; rr++) {
        qld[(orow + rr) * 72 + (ct << 4) + fr] = f2b(aq[ct][rr]);
        kld[(orow + rr) * 72 + (ct << 4) + fr] = f2b(ak[ct][rr]);
      }
      u16x4 vp;
      vp.x = f2b(av[ct][0]);
      vp.y = f2b(av[ct][1]);
      vp.z = f2b(av[ct][2]);
      vp.w = f2b(av[ct][3]);
      *(u16x4*)&vtl[((ct << 4) + fr) * 72 + orow] = vp;
    }
  }
  __syncthreads();

  {
    bf16x8 aq[2];
#pragma unroll
    for (int ks = 0; ks < 2; ks++)
      aq[ks] = *(const bf16x8*)&qld[((w << 4) + fr) * 72 + (ks << 5) + (fq << 3)];
    f32x4 accs[4];
#pragma unroll
    for (int nt = 0; nt < 4; nt++) accs[nt] = (f32x4){0.f, 0.f, 0.f, 0.f};
#pragma unroll
    for (int nt = 0; nt < 4; nt++)
#pragma unroll
      for (int ks = 0; ks < 2; ks++) {
        bf16x8 bk = *(const bf16x8*)&kld[((nt << 4) + fr) * 72 + (ks << 5) + (fq << 3)];
        accs[nt] = __builtin_amdgcn_mfma_f32_16x16x32_bf16(aq[ks], bk, accs[nt], 0, 0, 0);
      }
#pragma unroll
    for (int rr = 0; rr < 4; rr++) {
      float v0 = accs[0][rr] * 0.125f, v1 = accs[1][rr] * 0.125f;
      float v2 = accs[2][rr] * 0.125f, v3 = accs[3][rr] * 0.125f;
      float mx = fmaxf(fmaxf(v0, v1), fmaxf(v2, v3));
      mx = fmaxf(mx, __shfl_xor(mx, 1));
      mx = fmaxf(mx, __shfl_xor(mx, 2));
      mx = fmaxf(mx, __shfl_xor(mx, 4));
      mx = fmaxf(mx, __shfl_xor(mx, 8));
      float e0 = expf(v0 - mx), e1 = expf(v1 - mx);
      float e2 = expf(v2 - mx), e3 = expf(v3 - mx);
      float ss = e0 + e1 + e2 + e3;
      ss += __shfl_xor(ss, 1);
      ss += __shfl_xor(ss, 2);
      ss += __shfl_xor(ss, 4);
      ss += __shfl_xor(ss, 8);
      float inv = 1.0f / ss;
      stb[(orow + rr) * 72 + 0 * 16 + fr] = f2b(e0 * inv);
      stb[(orow + rr) * 72 + 1 * 16 + fr] = f2b(e1 * inv);
      stb[(orow + rr) * 72 + 2 * 16 + fr] = f2b(e2 * inv);
      stb[(orow + rr) * 72 + 3 * 16 + fr] = f2b(e3 * inv);
    }
  }
  __syncthreads();

  float o16[4][4];
  {
    bf16x8 ap[2];
#pragma unroll
    for (int ks = 0; ks < 2; ks++)
      ap[ks] = *(const bf16x8*)&stb[((w << 4) + fr) * 72 + (ks << 5) + (fq << 3)];
    f32x4 acco[4];
#pragma unroll
    for (int ct = 0; ct < 4; ct++) acco[ct] = (f32x4){0.f, 0.f, 0.f, 0.f};
#pragma unroll
    for (int ct = 0; ct < 4; ct++)
#pragma unroll
      for (int ks = 0; ks < 2; ks++) {
        bf16x8 bv = *(const bf16x8*)&vtl[((ct << 4) + fr) * 72 + (ks << 5) + (fq << 3)];
        acco[ct] = __builtin_amdgcn_mfma_f32_16x16x32_bf16(ap[ks], bv, acco[ct], 0, 0, 0);
      }
    float tgv[4], tbv[4];
#pragma unroll
    for (int ct = 0; ct < 4; ct++) {
      tgv[ct] = tg[(ct << 4) + fr];
      tbv[ct] = tb[(ct << 4) + fr];
    }
#pragma unroll
    for (int ct = 0; ct < 4; ct++)
#pragma unroll
      for (int rr = 0; rr < 4; rr++)
        o16[ct][rr] = acco[ct][rr] + st32[(orow + rr) * 68 + (ct << 4) + fr];
#pragma unroll
    for (int rr = 0; rr < 4; rr++) {
      float sm = o16[0][rr] + o16[1][rr] + o16[2][rr] + o16[3][rr];
      float sq = o16[0][rr] * o16[0][rr] + o16[1][rr] * o16[1][rr] +
                 o16[2][rr] * o16[2][rr] + o16[3][rr] * o16[3][rr];
      sm += __shfl_xor(sm, 1);
      sm += __shfl_xor(sm, 2);
      sm += __shfl_xor(sm, 4);
      sm += __shfl_xor(sm, 8);
      sq += __shfl_xor(sq, 1);
      sq += __shfl_xor(sq, 2);
      sq += __shfl_xor(sq, 4);
      sq += __shfl_xor(sq, 8);
      float mean = sm * (1.0f / 64.0f);
      float var = sq * (1.0f / 64.0f) - mean * mean;
      float rstd = rsqrtf(var + 1e-5f);
#pragma unroll
      for (int ct = 0; ct < 4; ct++) {
        float hv = (o16[ct][rr] - mean) * rstd * tgv[ct] + tbv[ct];
        qld[(orow + rr) * 72 + (ct << 4) + fr] = f2b(hv);
      }
    }
  }
  __syncthreads();

  {
    bf16x8 ah[2];
#pragma unroll
    for (int ks = 0; ks < 2; ks++)
      ah[ks] = *(const bf16x8*)&qld[((w << 4) + fr) * 72 + (ks << 5) + (fq << 3)];
    f32x4 accm[8];
#pragma unroll
    for (int et = 0; et < 8; et++) accm[et] = (f32x4){0.f, 0.f, 0.f, 0.f};
#pragma unroll
    for (int et = 0; et < 8; et++)
#pragma unroll
      for (int ks = 0; ks < 2; ks++) {
        bf16x8 bm = *(const bf16x8*)&wfr[((24 + (et << 1) + ks) * 64 + l) * 8];
        accm[et] = __builtin_amdgcn_mfma_f32_16x16x32_bf16(ah[ks], bm, accm[et], 0, 0, 0);
      }
#pragma unroll
    for (int et = 0; et < 8; et++) {
      float bv = bm1[(et << 4) + fr];
#pragma unroll
      for (int rr = 0; rr < 4; rr++) {
        float x = accm[et][rr] + bv;
        hmld[(orow + rr) * 136 + (et << 4) + fr] = f2b(gelu_exact(x));
      }
    }
  }
  __syncthreads();

  {
    bf16x8 ahm[4];
#pragma unroll
    for (int ks = 0; ks < 4; ks++)
      ahm[ks] = *(const bf16x8*)&hmld[((w << 4) + fr) * 136 + (ks << 5) + (fq << 3)];
    f32x4 acc2[4];
#pragma unroll
    for (int ct = 0; ct < 4; ct++) acc2[ct] = (f32x4){0.f, 0.f, 0.f, 0.f};
#pragma unroll
    for (int ct = 0; ct < 4; ct++)
#pragma unroll
      for (int ks = 0; ks < 4; ks++) {
        bf16x8 bw = *(const bf16x8*)&wfr[((40 + (ct << 2) + ks) * 64 + l) * 8];
        acc2[ct] = __builtin_amdgcn_mfma_f32_16x16x32_bf16(ahm[ks], bw, acc2[ct], 0, 0, 0);
      }
    float* tout = tokens + ((size_t)bh << 12);
#pragma unroll
    for (int ct = 0; ct < 4; ct++) {
      float bv = bm2[(ct << 4) + fr];
#pragma unroll
      for (int rr = 0; rr < 4; rr++)
        tout[(orow + rr) * 64 + (ct << 4) + fr] = acc2[ct][rr] + bv + o16[ct][rr];
    }
  }
}

// ---------------------------------------------------------------------------
// K8: deslice via MFMA, zero LDS (unchanged).
// ---------------------------------------------------------------------------
__global__ __launch_bounds__(256) void deslice_mfma(
    const unsigned short* __restrict__ wtokf, const unsigned short* __restrict__ sw,
    unsigned short* __restrict__ outx) {
  int bid = blockIdx.x;
  int bh = bid >> 4, c = bid & 15;
  int b = bh >> 3, h = bh & 7;
  int t = threadIdx.x, w = t >> 6, l = t & 63;
  const int fr = l & 15, fq = l >> 4;

  bf16x8 ta[4][2];
  const unsigned short* fp = wtokf + ((size_t)bh << 12);
#pragma unroll
  for (int mt = 0; mt < 4; mt++)
#pragma unroll
    for (int ks = 0; ks < 2; ks++)
      ta[mt][ks] = *(const bf16x8*)(fp + (((mt << 1) + ks) << 9) + (l << 3));

  int n0 = (c << 9) + (w << 7);
#pragma unroll 2
  for (int ntile = 0; ntile < 8; ntile++) {
    int nb = n0 + (ntile << 4);
    size_t rowb = ((size_t)(b * N_ + nb + fr) * 8 + h) << 6;
    bf16x8 b0 = *(const bf16x8*)(sw + rowb + (fq << 3));
    bf16x8 b1 = *(const bf16x8*)(sw + rowb + 32 + (fq << 3));
    f32x4 acc[4];
#pragma unroll
    for (int mt = 0; mt < 4; mt++) acc[mt] = (f32x4){0.f, 0.f, 0.f, 0.f};
#pragma unroll
    for (int mt = 0; mt < 4; mt++) {
      acc[mt] = __builtin_amdgcn_mfma_f32_16x16x32_bf16(ta[mt][0], b0, acc[mt], 0, 0, 0);
      acc[mt] = __builtin_amdgcn_mfma_f32_16x16x32_bf16(ta[mt][1], b1, acc[mt], 0, 0, 0);
    }
    unsigned short* op = outx + rowb + (fq << 2);
#pragma unroll
    for (int mt = 0; mt < 4; mt++) {
      u16x4 pk;
      pk.x = f2b(acc[mt][0]);
      pk.y = f2b(acc[mt][1]);
      pk.z = f2b(acc[mt][2]);
      pk.w = f2b(acc[mt][3]);
      *(u16x4*)(op + (mt << 4)) = pk;
    }
  }
}

// ---------------------------------------------------------------------------
extern "C" void kernel_launch(void* const* d_in, const int* in_sizes, int n_in,
                              void* d_out, int out_size, void* d_ws,
                              size_t ws_size, hipStream_t stream) {
  const float* fx = (const float*)d_in[0];
  const float* ln1g = (const float*)d_in[1];
  const float* ln1b = (const float*)d_in[2];
  const float* Wx = (const float*)d_in[3];
  const float* bx = (const float*)d_in[4];
  const float* Wfx = (const float*)d_in[5];
  const float* bfx = (const float*)d_in[6];
  const float* Wsl = (const float*)d_in[7];
  const float* bsl = (const float*)d_in[8];
  const float* temp = (const float*)d_in[9];
  const float* Wq = (const float*)d_in[10];
  const float* Wk = (const float*)d_in[11];
  const float* Wv = (const float*)d_in[12];
  const float* Wout = (const float*)d_in[13];
  const float* bout = (const float*)d_in[14];
  const float* tlng = (const float*)d_in[15];
  const float* tlnb = (const float*)d_in[16];
  const float* Wm1 = (const float*)d_in[17];
  const float* bm1 = (const float*)d_in[18];
  const float* Wm2 = (const float*)d_in[19];
  const float* bm2 = (const float*)d_in[20];
  float* out = (float*)d_out;

  char* p = (char*)d_ws;
  const size_t MC2 = (size_t)M_ * 512 * 2;
  unsigned short* fxn = (unsigned short*)p;  p += MC2;
  unsigned short* buf1 = (unsigned short*)p; p += MC2;  // x_mid -> slice_w
  unsigned short* bufT = (unsigned short*)p; p += MC2;  // fxT -> out_x
  unsigned short* WtX = (unsigned short*)p;  p += 512 * 512 * 2;
  unsigned short* WtF = (unsigned short*)p;  p += 512 * 512 * 2;
  unsigned short* WtO = (unsigned short*)p;  p += 512 * 512 * 2;
  unsigned short* wsf = (unsigned short*)p;  p += 8192;
  unsigned short* wfr = (unsigned short*)p;  p += 56 * 512 * 2;
  unsigned short* wtokf = (unsigned short*)p; p += (size_t)32 * 8 * 512 * 2;
  float* tok_part = (float*)p;  p += (size_t)512 * 4096 * 4;
  float* norm_part = (float*)p; p += (size_t)512 * 64 * 4;
  float* tokens = (float*)p;    p += (size_t)32 * 4096 * 4;
  float* stG = (float*)p;       p += (size_t)32 * 4096 * 4;

  ln_bf16<<<M_ / 4, 256, 0, stream>>>(fx, ln1g, ln1b, fxn);
  prep_all<<<193, 256, 0, stream>>>(Wx, Wfx, Wout, Wsl, Wq, Wk, Wv, Wm1, Wm2,
                                    WtX, WtF, WtO, wsf, wfr);
  gemm_bf16<0, false, true, false><<<1024, 256, 0, stream>>>(fxn, WtX, bx, nullptr, buf1, 512);
  gemm_bf16<1, true, true, false><<<1024, 256, 0, stream>>>(WtF, fxn, bfx, nullptr, bufT, 32768);
  slice_mfma<<<4096, 256, 0, stream>>>(buf1, wsf, bsl, temp);
  pool_mfma<<<512, 256, 0, stream>>>(buf1, bufT, tok_part, norm_part);
  tok_reduce<<<128, 256, 0, stream>>>(tok_part, norm_part, stG);
  token_mfma<<<32, 256, 0, stream>>>(stG, wfr, tlng, tlnb, bm1, bm2, tokens);
  tokfrag_prep<<<32, 256, 0, stream>>>(tokens, wtokf);
  deslice_mfma<<<512, 256, 0, stream>>>(wtokf, buf1, bufT);
  gemm_bf16<0, false, false, true><<<1024, 256, 0, stream>>>(bufT, WtO, bout, fxn, out, 512);
}

// Round 9
// 172.544 us; speedup vs baseline: 1.0737x; 1.0737x over previous
//
#include <hip/hip_runtime.h>
#include <math.h>

#define B_ 4
#define N_ 8192
#define C_ 512
#define H_ 8
#define M_ (B_ * N_) /* 32768 */

typedef __attribute__((ext_vector_type(8))) short bf16x8;
typedef __attribute__((ext_vector_type(4))) float f32x4;
typedef __attribute__((ext_vector_type(8))) unsigned short u16x8;
typedef __attribute__((ext_vector_type(4))) unsigned short u16x4;

__device__ __forceinline__ float b2f(unsigned short u) {
  union { unsigned int i; float f; } v;
  v.i = ((unsigned int)u) << 16;
  return v.f;
}
__device__ __forceinline__ unsigned short f2b(float f) {
  union { float f; unsigned int i; } v;
  v.f = f;
  unsigned int r = v.i + 0x7fff + ((v.i >> 16) & 1);
  return (unsigned short)(r >> 16);
}
__device__ __forceinline__ void gl_lds16(const void* g, void* l) {
  __builtin_amdgcn_global_load_lds(
      (const __attribute__((address_space(1))) unsigned int*)g,
      (__attribute__((address_space(3))) unsigned int*)l, 16, 0, 0);
}

// ---------------------------------------------------------------------------
// K1: LayerNorm over C=512 -> bf16. One wave per row.
// ---------------------------------------------------------------------------
__global__ __launch_bounds__(256) void ln_bf16(
    const float* __restrict__ x, const float* __restrict__ gam,
    const float* __restrict__ bet, unsigned short* __restrict__ y) {
  int wave = threadIdx.x >> 6, lane = threadIdx.x & 63;
  int row = (blockIdx.x << 2) + wave;
  const float4* xr = (const float4*)(x + (size_t)row * C_);
  float4 v0 = xr[lane], v1 = xr[lane + 64];
  float s = v0.x + v0.y + v0.z + v0.w + v1.x + v1.y + v1.z + v1.w;
  float q = v0.x * v0.x + v0.y * v0.y + v0.z * v0.z + v0.w * v0.w +
            v1.x * v1.x + v1.y * v1.y + v1.z * v1.z + v1.w * v1.w;
#pragma unroll
  for (int off = 32; off; off >>= 1) {
    s += __shfl_xor(s, off);
    q += __shfl_xor(q, off);
  }
  float mean = s * (1.0f / C_);
  float var = q * (1.0f / C_) - mean * mean;
  float rstd = rsqrtf(var + 1e-5f);
  const float4* gr = (const float4*)gam;
  const float4* br = (const float4*)bet;
  float4 g0 = gr[lane], g1 = gr[lane + 64];
  float4 b0 = br[lane], b1 = br[lane + 64];
  u16x4 oa, ob;
  oa.x = f2b((v0.x - mean) * rstd * g0.x + b0.x);
  oa.y = f2b((v0.y - mean) * rstd * g0.y + b0.y);
  oa.z = f2b((v0.z - mean) * rstd * g0.z + b0.z);
  oa.w = f2b((v0.w - mean) * rstd * g0.w + b0.w);
  ob.x = f2b((v1.x - mean) * rstd * g1.x + b1.x);
  ob.y = f2b((v1.y - mean) * rstd * g1.y + b1.y);
  ob.z = f2b((v1.z - mean) * rstd * g1.z + b1.z);
  ob.w = f2b((v1.w - mean) * rstd * g1.w + b1.w);
  unsigned short* yr = y + (size_t)row * C_;
  *(u16x4*)(yr + (lane << 2)) = oa;
  *(u16x4*)(yr + 256 + (lane << 2)) = ob;
}

// ---------------------------------------------------------------------------
// K2: merged prep (weight transposes + frag precomputes).
// ---------------------------------------------------------------------------
__global__ __launch_bounds__(256) void prep_all(
    const float* __restrict__ Wx, const float* __restrict__ Wfx,
    const float* __restrict__ Wout, const float* __restrict__ Wsl,
    const float* __restrict__ Wq, const float* __restrict__ Wk,
    const float* __restrict__ Wv, const float* __restrict__ Wm1,
    const float* __restrict__ Wm2, unsigned short* __restrict__ WtX,
    unsigned short* __restrict__ WtF, unsigned short* __restrict__ WtO,
    unsigned short* __restrict__ wsf, unsigned short* __restrict__ wfr) {
  __shared__ float tile[64][65];
  int blk = blockIdx.x, t = threadIdx.x;
  if (blk < 192) {
    int which = blk >> 6, sub = blk & 63;
    const float* W = (which == 0) ? Wx : (which == 1) ? Wfx : Wout;
    unsigned short* Wt = (which == 0) ? WtX : (which == 1) ? WtF : WtO;
    int r0 = (sub >> 3) << 6, c0 = (sub & 7) << 6;
    int lr = t >> 4, lc = (t & 15) << 2;
#pragma unroll
    for (int p = 0; p < 4; p++) {
      float4 v = *(const float4*)(W + (size_t)(r0 + lr + p * 16) * 512 + c0 + lc);
      tile[lr + p * 16][lc + 0] = v.x;
      tile[lr + p * 16][lc + 1] = v.y;
      tile[lr + p * 16][lc + 2] = v.z;
      tile[lr + p * 16][lc + 3] = v.w;
    }
    __syncthreads();
    int on = t >> 2, ok = (t & 3) << 4;
    unsigned short tmp[16];
#pragma unroll
    for (int j = 0; j < 16; j++) tmp[j] = f2b(tile[ok + j][on]);
    unsigned short* op = Wt + (size_t)(c0 + on) * 512 + r0 + ok;
#pragma unroll
    for (int j4 = 0; j4 < 4; j4++)
      *(u16x4*)(op + (j4 << 2)) = *(u16x4*)(tmp + (j4 << 2));
  } else {
#pragma unroll
    for (int i = 0; i < 2; i++) {
      int idx = t + i * 256;
      int f = idx >> 6, l = idx & 63;
      int gt = f >> 1, ks = f & 1;
      int g = (gt << 4) + (l & 15);
      int d0 = (ks << 5) + ((l >> 4) << 3);
      unsigned short v[8];
#pragma unroll
      for (int jj = 0; jj < 8; jj++) v[jj] = f2b(Wsl[(size_t)(d0 + jj) * 64 + g]);
      *(u16x4*)(wsf + idx * 8) = *(u16x4*)v;
      *(u16x4*)(wsf + idx * 8 + 4) = *(u16x4*)(v + 4);
    }
    for (int task = t; task < 56 * 64; task += 256) {
      int fid = task >> 6, l = task & 63;
      const float* W;
      int stride, ct, ks;
      if (fid < 24) {
        W = (fid < 8) ? Wq : (fid < 16) ? Wk : Wv;
        int e = fid & 7;
        ct = e >> 1;
        ks = e & 1;
        stride = 64;
      } else if (fid < 40) {
        W = Wm1;
        int e = fid - 24;
        ct = e >> 1;
        ks = e & 1;
        stride = 128;
      } else {
        W = Wm2;
        int e = fid - 40;
        ct = e >> 2;
        ks = e & 3;
        stride = 64;
      }
      int d0 = (ks << 5) + ((l >> 4) << 3);
      int c = (ct << 4) + (l & 15);
      unsigned short v[8];
#pragma unroll
      for (int j = 0; j < 8; j++) v[j] = f2b(W[(size_t)(d0 + j) * stride + c]);
      *(u16x4*)(wfr + task * 8) = *(u16x4*)v;
      *(u16x4*)(wfr + task * 8 + 4) = *(u16x4*)(v + 4);
    }
  }
}

// ---------------------------------------------------------------------------
// K4: bf16 MFMA GEMM, single-buffer, BK=64 (8 K-iters, 32 KB LDS; grid is
// 4 blocks/CU so the LDS doubling costs no occupancy). Slot swizzle:
// A/B tiles [128][64] u16, phys 16B-slot = logical ^ (row&7).
// ---------------------------------------------------------------------------
template <int DEC, bool BIASROW, bool OUTBF, bool RES>
__global__ __launch_bounds__(256) void gemm_bf16(
    const unsigned short* __restrict__ A, const unsigned short* __restrict__ Bt,
    const float* __restrict__ bias, const unsigned short* __restrict__ resid,
    void* __restrict__ Cout, size_t ldC) {
  __shared__ unsigned short lds[16384];  // A [128][64] @0, B @8192
  const int t = threadIdx.x;
  const int w = t >> 6, l = t & 63;
  int bid = blockIdx.x;
  int xcd = bid & 7, q = bid >> 3;
  int bm, bn;
  if (DEC == 0) {
    bm = ((xcd << 5) + (q >> 2)) << 7;
    bn = (q & 3) << 7;
  } else {
    bn = ((xcd << 5) + (q >> 2)) << 7;
    bm = (q & 3) << 7;
  }
  const int wm = (w >> 1) << 6, wn = (w & 1) << 6;
  f32x4 acc[4][4];
#pragma unroll
  for (int mt = 0; mt < 4; mt++)
#pragma unroll
    for (int nt = 0; nt < 4; nt++) acc[mt][nt] = (f32x4){0.f, 0.f, 0.f, 0.f};

  const int srow = t >> 3;  // 0..31 (row within 32-row chunk)
  const int scol = (((t & 7) ^ ((t >> 3) & 7)) << 3);  // swizzled source slot
  const unsigned short* gA = A + (size_t)(bm + srow) * 512 + scol;
  const unsigned short* gB = Bt + (size_t)(bn + srow) * 512 + scol;
  const int fr = l & 15, qq = l >> 4;

  for (int k0 = 0; k0 < 512; k0 += 64) {
#pragma unroll
    for (int i = 0; i < 4; i++)
      gl_lds16(gA + (size_t)(i << 5) * 512 + k0, lds + (i << 11) + (w << 9));
#pragma unroll
    for (int i = 0; i < 4; i++)
      gl_lds16(gB + (size_t)(i << 5) * 512 + k0, lds + 8192 + (i << 11) + (w << 9));
    __syncthreads();
#pragma unroll
    for (int kk = 0; kk < 2; kk++) {
      bf16x8 af[4], bfr[4];
#pragma unroll
      for (int mt = 0; mt < 4; mt++) {
        int row = wm + mt * 16 + fr;
        af[mt] = *(const bf16x8*)&lds[row * 64 + ((((kk << 2) + qq) ^ (fr & 7)) << 3)];
      }
#pragma unroll
      for (int nt = 0; nt < 4; nt++) {
        int row = wn + nt * 16 + fr;
        bfr[nt] = *(const bf16x8*)&lds[8192 + row * 64 + ((((kk << 2) + qq) ^ (fr & 7)) << 3)];
      }
#pragma unroll
      for (int mt = 0; mt < 4; mt++)
#pragma unroll
        for (int nt = 0; nt < 4; nt++)
          acc[mt][nt] = __builtin_amdgcn_mfma_f32_16x16x32_bf16(
              af[mt], bfr[nt], acc[mt][nt], 0, 0, 0);
    }
    __syncthreads();
  }

  const int col0 = bn + wn + (l & 15);
  const int row0 = bm + wm + ((l >> 4) << 2);
#pragma unroll
  for (int mt = 0; mt < 4; mt++) {
#pragma unroll
    for (int j = 0; j < 4; j++) {
      int row = row0 + mt * 16 + j;
#pragma unroll
      for (int nt = 0; nt < 4; nt++) {
        int col = col0 + nt * 16;
        float v = acc[mt][nt][j] + (BIASROW ? bias[row] : bias[col]);
        if (RES) v += b2f(resid[(size_t)row * ldC + col]);
        if (OUTBF)
          ((unsigned short*)Cout)[(size_t)row * ldC + col] = f2b(v);
        else
          ((float*)Cout)[(size_t)row * ldC + col] = v;
      }
    }
  }
}

// ---------------------------------------------------------------------------
// K5: slice softmax via MFMA (unchanged, in place over x_mid).
// ---------------------------------------------------------------------------
__global__ __launch_bounds__(256) void slice_mfma(
    unsigned short* __restrict__ xw, const unsigned short* __restrict__ wf,
    const float* __restrict__ bslice, const float* __restrict__ temp) {
  __shared__ unsigned short xs[4096];
  int t = threadIdx.x, w = t >> 6, l = t & 63;
  int blk = blockIdx.x;
  size_t base = (size_t)blk << 12;
  {
    int srow = t >> 2;
    const unsigned short* gp = xw + base + srow * 64 + ((t & 3) << 4);
    u16x8 a = *(const u16x8*)gp;
    u16x8 b = *(const u16x8*)(gp + 8);
    int sl0 = (t & 3) << 1, swz = srow & 7;
    *(u16x8*)&xs[srow * 64 + ((sl0 ^ swz) << 3)] = a;
    *(u16x8*)&xs[srow * 64 + (((sl0 + 1) ^ swz) << 3)] = b;
  }
  bf16x8 wsf[4][2];
#pragma unroll
  for (int gt = 0; gt < 4; gt++)
#pragma unroll
    for (int ks = 0; ks < 2; ks++)
      wsf[gt][ks] = *(const bf16x8*)(wf + (((gt << 1) + ks) * 64 + l) * 8);
  __syncthreads();

  int xr = (w << 4) + (l & 15);
  f32x4 acc[4];
#pragma unroll
  for (int gt = 0; gt < 4; gt++) acc[gt] = (f32x4){0.f, 0.f, 0.f, 0.f};
#pragma unroll
  for (int ks = 0; ks < 2; ks++) {
    int slot = (ks << 2) + (l >> 4);
    bf16x8 xf = *(const bf16x8*)&xs[xr * 64 + ((slot ^ (xr & 7)) << 3)];
#pragma unroll
    for (int gt = 0; gt < 4; gt++)
      acc[gt] = __builtin_amdgcn_mfma_f32_16x16x32_bf16(wsf[gt][ks], xf,
                                                        acc[gt], 0, 0, 0);
  }

  int gxr = (blk << 6) + xr;
  float invt = 1.0f / temp[gxr & 7];
  int qq = l >> 4;
  float lg[16];
  float mx = -1e30f;
#pragma unroll
  for (int gt = 0; gt < 4; gt++)
#pragma unroll
    for (int r = 0; r < 4; r++) {
      float v = (acc[gt][r] + bslice[(gt << 4) + (qq << 2) + r]) * invt;
      lg[(gt << 2) + r] = v;
      mx = fmaxf(mx, v);
    }
  mx = fmaxf(mx, __shfl_xor(mx, 16));
  mx = fmaxf(mx, __shfl_xor(mx, 32));
  float ssum = 0.f;
#pragma unroll
  for (int i = 0; i < 16; i++) {
    lg[i] = expf(lg[i] - mx);
    ssum += lg[i];
  }
  ssum += __shfl_xor(ssum, 16);
  ssum += __shfl_xor(ssum, 32);
  float inv = 1.0f / ssum;
  __syncthreads();
#pragma unroll
  for (int gt = 0; gt < 4; gt++) {
    int slot = (gt << 1) + (qq >> 1);
    int off = ((slot ^ (xr & 7)) << 3) + ((qq & 1) << 2);
    u16x4 pk;
    pk.x = f2b(lg[(gt << 2) + 0] * inv);
    pk.y = f2b(lg[(gt << 2) + 1] * inv);
    pk.z = f2b(lg[(gt << 2) + 2] * inv);
    pk.w = f2b(lg[(gt << 2) + 3] * inv);
    *(u16x4*)&xs[xr * 64 + off] = pk;
  }
  __syncthreads();
  {
    int rr = (w << 4) + (l >> 2);
    int sl = (l & 3) << 1, swz = rr & 7;
    u16x8 o0 = *(const u16x8*)&xs[rr * 64 + ((sl ^ swz) << 3)];
    u16x8 o1 = *(const u16x8*)&xs[rr * 64 + (((sl + 1) ^ swz) << 3)];
    unsigned short* op = xw + base + rr * 64 + ((l & 3) << 4);
    *(u16x8*)op = o0;
    *(u16x8*)(op + 8) = o1;
  }
}

// ---------------------------------------------------------------------------
// K6: pool via MFMA (unchanged).
// ---------------------------------------------------------------------------
__global__ __launch_bounds__(256) void pool_mfma(
    const unsigned short* __restrict__ sw, const unsigned short* __restrict__ fxT,
    float* __restrict__ tok_part, float* __restrict__ norm_part) {
  __shared__ unsigned short wT[4096];
  int bid = blockIdx.x;
  int bh = bid >> 4, c = bid & 15;
  int b = bh >> 3, h = bh & 7;
  int t = threadIdx.x, w = t >> 6, l = t & 63;
  int n0 = c << 9;
  const int fr15 = l & 15, fs = l >> 4;
  f32x4 acc[4];
#pragma unroll
  for (int gt = 0; gt < 4; gt++) acc[gt] = (f32x4){0.f, 0.f, 0.f, 0.f};
  float nacc[4] = {0.f, 0.f, 0.f, 0.f};

  const unsigned short* fxrow =
      fxT + (size_t)(h * 64 + w * 16 + fr15) * 32768 + b * N_ + n0 + (fs << 3);

  for (int nn = 0; nn < 512; nn += 64) {
    size_t srow = ((size_t)(b * N_ + n0 + nn + l) * 8 + h) << 6;
    u16x8 a0 = *(const u16x8*)(sw + srow + w * 16);
    u16x8 a1 = *(const u16x8*)(sw + srow + w * 16 + 8);
    __syncthreads();
#pragma unroll
    for (int j = 0; j < 16; j++) {
      int g = (w << 4) + j;
      unsigned short v = (j < 8) ? (unsigned short)a0[j] : (unsigned short)a1[j - 8];
      wT[(g << 6) + (((l >> 3) ^ (g & 7)) << 3) + (l & 7)] = v;
    }
    __syncthreads();
#pragma unroll
    for (int kk = 0; kk < 2; kk++) {
      bf16x8 bfrag = *(const bf16x8*)(fxrow + nn + (kk << 5));
#pragma unroll
      for (int gt = 0; gt < 4; gt++) {
        int g = (gt << 4) + fr15;
        int slot = (kk << 2) + fs;
        bf16x8 af = *(const bf16x8*)&wT[(g << 6) + ((slot ^ (g & 7)) << 3)];
        acc[gt] = __builtin_amdgcn_mfma_f32_16x16x32_bf16(af, bfrag, acc[gt], 0, 0, 0);
        if (w == 0) {
#pragma unroll
          for (int j = 0; j < 8; j++) nacc[gt] += b2f((unsigned short)af[j]);
        }
      }
    }
  }
  float* op = tok_part + ((size_t)bid << 12);
#pragma unroll
  for (int gt = 0; gt < 4; gt++)
#pragma unroll
    for (int rr = 0; rr < 4; rr++)
      op[((gt << 4) + (fs << 2) + rr) * 64 + (w << 4) + fr15] = acc[gt][rr];
  if (w == 0) {
#pragma unroll
    for (int gt = 0; gt < 4; gt++) {
      float s = nacc[gt];
      s += __shfl_xor(s, 16);
      s += __shfl_xor(s, 32);
      if (l < 16) norm_part[(bid << 6) + (gt << 4) + l] = s;
    }
  }
}

// ---------------------------------------------------------------------------
// K6b: reduce tok_part chunks + norm_part -> normalized slice_tok fp32.
// ---------------------------------------------------------------------------
__global__ __launch_bounds__(256) void tok_reduce(
    const float* __restrict__ tok_part, const float* __restrict__ norm_part,
    float* __restrict__ stG) {
  int blk = blockIdx.x;
  int bh = blk >> 2, qq = blk & 3;
  int t = threadIdx.x;
  int e = (qq << 10) + (t << 2);
  int g = e >> 6;
  float s = 0.f;
  const float* np = norm_part + ((size_t)bh << 10);
#pragma unroll
  for (int c = 0; c < 16; c++) s += np[(c << 6) + g];
  float4 acc = make_float4(0.f, 0.f, 0.f, 0.f);
  const float* tp = tok_part + ((size_t)bh << 16) + e;
#pragma unroll
  for (int c = 0; c < 16; c++) {
    float4 v = *(const float4*)(tp + (c << 12));
    acc.x += v.x;
    acc.y += v.y;
    acc.z += v.z;
    acc.w += v.w;
  }
  float inv = 1.0f / (s + 1e-5f);
  acc.x *= inv;
  acc.y *= inv;
  acc.z *= inv;
  acc.w *= inv;
  *(float4*)(stG + ((size_t)bh << 12) + e) = acc;
}

// ---------------------------------------------------------------------------
// K7: token pipeline via MFMA + fused deslice-fragment emit (tokens never
// touch global; wtokf written directly from LDS).
// ---------------------------------------------------------------------------
__device__ __forceinline__ float gelu_exact(float x) {
  return 0.5f * x * (1.0f + erff(x * 0.70710678118654752f));
}

__global__ __launch_bounds__(256) void token_mfma(
    const float* __restrict__ stG, const unsigned short* __restrict__ wfr,
    const float* __restrict__ tg, const float* __restrict__ tb,
    const float* __restrict__ bm1, const float* __restrict__ bm2,
    unsigned short* __restrict__ wtokf) {
  __shared__ __align__(16) char smem[54272];
  unsigned short* stb = (unsigned short*)smem;            // slice_tok -> P -> tokens
  float* st32 = (float*)(smem + 9216);
  unsigned short* hmld = (unsigned short*)(smem + 9216);
  unsigned short* qld = (unsigned short*)(smem + 26624);
  unsigned short* kld = (unsigned short*)(smem + 35840);
  unsigned short* vtl = (unsigned short*)(smem + 45056);

  int bh = blockIdx.x, t = threadIdx.x, w = t >> 6, l = t & 63;
  const int fr = l & 15, fq = l >> 4;

  {
    int r = t >> 2, c0 = (t & 3) << 4;
    const float* gp = stG + ((size_t)bh << 12) + r * 64 + c0;
    float4 a = *(const float4*)gp;
    float4 b = *(const float4*)(gp + 4);
    float4 c = *(const float4*)(gp + 8);
    float4 d = *(const float4*)(gp + 12);
    *(float4*)&st32[r * 68 + c0] = a;
    *(float4*)&st32[r * 68 + c0 + 4] = b;
    *(float4*)&st32[r * 68 + c0 + 8] = c;
    *(float4*)&st32[r * 68 + c0 + 12] = d;
    unsigned short tv[16];
    tv[0] = f2b(a.x); tv[1] = f2b(a.y); tv[2] = f2b(a.z); tv[3] = f2b(a.w);
    tv[4] = f2b(b.x); tv[5] = f2b(b.y); tv[6] = f2b(b.z); tv[7] = f2b(b.w);
    tv[8] = f2b(c.x); tv[9] = f2b(c.y); tv[10] = f2b(c.z); tv[11] = f2b(c.w);
    tv[12] = f2b(d.x); tv[13] = f2b(d.y); tv[14] = f2b(d.z); tv[15] = f2b(d.w);
    *(u16x8*)&stb[r * 72 + c0] = *(u16x8*)tv;
    *(u16x8*)&stb[r * 72 + c0 + 8] = *(u16x8*)(tv + 8);
  }
  __syncthreads();

  const int orow = (w << 4) + (fq << 2);

  {
    bf16x8 af[2];
#pragma unroll
    for (int ks = 0; ks < 2; ks++)
      af[ks] = *(const bf16x8*)&stb[((w << 4) + fr) * 72 + (ks << 5) + (fq << 3)];
    f32x4 aq[4], ak[4], av[4];
#pragma unroll
    for (int ct = 0; ct < 4; ct++) {
      aq[ct] = (f32x4){0.f, 0.f, 0.f, 0.f};
      ak[ct] = (f32x4){0.f, 0.f, 0.f, 0.f};
      av[ct] = (f32x4){0.f, 0.f, 0.f, 0.f};
    }
#pragma unroll
    for (int ct = 0; ct < 4; ct++)
#pragma unroll
      for (int ks = 0; ks < 2; ks++) {
        bf16x8 bq = *(const bf16x8*)&wfr[(((ct << 1) + ks) * 64 + l) * 8];
        aq[ct] = __builtin_amdgcn_mfma_f32_16x16x32_bf16(af[ks], bq, aq[ct], 0, 0, 0);
      }
#pragma unroll
    for (int ct = 0; ct < 4; ct++)
#pragma unroll
      for (int ks = 0; ks < 2; ks++) {
        bf16x8 bk = *(const bf16x8*)&wfr[((8 + (ct << 1) + ks) * 64 + l) * 8];
        ak[ct] = __builtin_amdgcn_mfma_f32_16x16x32_bf16(af[ks], bk, ak[ct], 0, 0, 0);
      }
#pragma unroll
    for (int ct = 0; ct < 4; ct++)
#pragma unroll
      for (int ks = 0; ks < 2; ks++) {
        bf16x8 bv = *(const bf16x8*)&wfr[((16 + (ct << 1) + ks) * 64 + l) * 8];
        av[ct] = __builtin_amdgcn_mfma_f32_16x16x32_bf16(af[ks], bv, av[ct], 0, 0, 0);
      }
#pragma unroll
    for (int ct = 0; ct < 4; ct++) {
#pragma unroll
      for (int rr = 0; rr < 4; rr++) {
        qld[(orow + rr) * 72 + (ct << 4) + fr] = f2b(aq[ct][rr]);
        kld[(orow + rr) * 72 + (ct << 4) + fr] = f2b(ak[ct][rr]);
      }
      u16x4 vp;
      vp.x = f2b(av[ct][0]);
      vp.y = f2b(av[ct][1]);
      vp.z = f2b(av[ct][2]);
      vp.w = f2b(av[ct][3]);
      *(u16x4*)&vtl[((ct << 4) + fr) * 72 + orow] = vp;
    }
  }
  __syncthreads();

  {
    bf16x8 aq[2];
#pragma unroll
    for (int ks = 0; ks < 2; ks++)
      aq[ks] = *(const bf16x8*)&qld[((w << 4) + fr) * 72 + (ks << 5) + (fq << 3)];
    f32x4 accs[4];
#pragma unroll
    for (int nt = 0; nt < 4; nt++) accs[nt] = (f32x4){0.f, 0.f, 0.f, 0.f};
#pragma unroll
    for (int nt = 0; nt < 4; nt++)
#pragma unroll
      for (int ks = 0; ks < 2; ks++) {
        bf16x8 bk = *(const bf16x8*)&kld[((nt << 4) + fr) * 72 + (ks << 5) + (fq << 3)];
        accs[nt] = __builtin_amdgcn_mfma_f32_16x16x32_bf16(aq[ks], bk, accs[nt], 0, 0, 0);
      }
#pragma unroll
    for (int rr = 0; rr < 4; rr++) {
      float v0 = accs[0][rr] * 0.125f, v1 = accs[1][rr] * 0.125f;
      float v2 = accs[2][rr] * 0.125f, v3 = accs[3][rr] * 0.125f;
      float mx = fmaxf(fmaxf(v0, v1), fmaxf(v2, v3));
      mx = fmaxf(mx, __shfl_xor(mx, 1));
      mx = fmaxf(mx, __shfl_xor(mx, 2));
      mx = fmaxf(mx, __shfl_xor(mx, 4));
      mx = fmaxf(mx, __shfl_xor(mx, 8));
      float e0 = expf(v0 - mx), e1 = expf(v1 - mx);
      float e2 = expf(v2 - mx), e3 = expf(v3 - mx);
      float ss = e0 + e1 + e2 + e3;
      ss += __shfl_xor(ss, 1);
      ss += __shfl_xor(ss, 2);
      ss += __shfl_xor(ss, 4);
      ss += __shfl_xor(ss, 8);
      float inv = 1.0f / ss;
      stb[(orow + rr) * 72 + 0 * 16 + fr] = f2b(e0 * inv);
      stb[(orow + rr) * 72 + 1 * 16 + fr] = f2b(e1 * inv);
      stb[(orow + rr) * 72 + 2 * 16 + fr] = f2b(e2 * inv);
      stb[(orow + rr) * 72 + 3 * 16 + fr] = f2b(e3 * inv);
    }
  }
  __syncthreads();

  float o16[4][4];
  {
    bf16x8 ap[2];
#pragma unroll
    for (int ks = 0; ks < 2; ks++)
      ap[ks] = *(const bf16x8*)&stb[((w << 4) + fr) * 72 + (ks << 5) + (fq << 3)];
    f32x4 acco[4];
#pragma unroll
    for (int ct = 0; ct < 4; ct++) acco[ct] = (f32x4){0.f, 0.f, 0.f, 0.f};
#pragma unroll
    for (int ct = 0; ct < 4; ct++)
#pragma unroll
      for (int ks = 0; ks < 2; ks++) {
        bf16x8 bv = *(const bf16x8*)&vtl[((ct << 4) + fr) * 72 + (ks << 5) + (fq << 3)];
        acco[ct] = __builtin_amdgcn_mfma_f32_16x16x32_bf16(ap[ks], bv, acco[ct], 0, 0, 0);
      }
    float tgv[4], tbv[4];
#pragma unroll
    for (int ct = 0; ct < 4; ct++) {
      tgv[ct] = tg[(ct << 4) + fr];
      tbv[ct] = tb[(ct << 4) + fr];
    }
#pragma unroll
    for (int ct = 0; ct < 4; ct++)
#pragma unroll
      for (int rr = 0; rr < 4; rr++)
        o16[ct][rr] = acco[ct][rr] + st32[(orow + rr) * 68 + (ct << 4) + fr];
#pragma unroll
    for (int rr = 0; rr < 4; rr++) {
      float sm = o16[0][rr] + o16[1][rr] + o16[2][rr] + o16[3][rr];
      float sq = o16[0][rr] * o16[0][rr] + o16[1][rr] * o16[1][rr] +
                 o16[2][rr] * o16[2][rr] + o16[3][rr] * o16[3][rr];
      sm += __shfl_xor(sm, 1);
      sm += __shfl_xor(sm, 2);
      sm += __shfl_xor(sm, 4);
      sm += __shfl_xor(sm, 8);
      sq += __shfl_xor(sq, 1);
      sq += __shfl_xor(sq, 2);
      sq += __shfl_xor(sq, 4);
      sq += __shfl_xor(sq, 8);
      float mean = sm * (1.0f / 64.0f);
      float var = sq * (1.0f / 64.0f) - mean * mean;
      float rstd = rsqrtf(var + 1e-5f);
#pragma unroll
      for (int ct = 0; ct < 4; ct++) {
        float hv = (o16[ct][rr] - mean) * rstd * tgv[ct] + tbv[ct];
        qld[(orow + rr) * 72 + (ct << 4) + fr] = f2b(hv);
      }
    }
  }
  __syncthreads();

  {
    bf16x8 ah[2];
#pragma unroll
    for (int ks = 0; ks < 2; ks++)
      ah[ks] = *(const bf16x8*)&qld[((w << 4) + fr) * 72 + (ks << 5) + (fq << 3)];
    f32x4 accm[8];
#pragma unroll
    for (int et = 0; et < 8; et++) accm[et] = (f32x4){0.f, 0.f, 0.f, 0.f};
#pragma unroll
    for (int et = 0; et < 8; et++)
#pragma unroll
      for (int ks = 0; ks < 2; ks++) {
        bf16x8 bm = *(const bf16x8*)&wfr[((24 + (et << 1) + ks) * 64 + l) * 8];
        accm[et] = __builtin_amdgcn_mfma_f32_16x16x32_bf16(ah[ks], bm, accm[et], 0, 0, 0);
      }
#pragma unroll
    for (int et = 0; et < 8; et++) {
      float bv = bm1[(et << 4) + fr];
#pragma unroll
      for (int rr = 0; rr < 4; rr++) {
        float x = accm[et][rr] + bv;
        hmld[(orow + rr) * 136 + (et << 4) + fr] = f2b(gelu_exact(x));
      }
    }
  }
  __syncthreads();

  {
    bf16x8 ahm[4];
#pragma unroll
    for (int ks = 0; ks < 4; ks++)
      ahm[ks] = *(const bf16x8*)&hmld[((w << 4) + fr) * 136 + (ks << 5) + (fq << 3)];
    f32x4 acc2[4];
#pragma unroll
    for (int ct = 0; ct < 4; ct++) acc2[ct] = (f32x4){0.f, 0.f, 0.f, 0.f};
#pragma unroll
    for (int ct = 0; ct < 4; ct++)
#pragma unroll
      for (int ks = 0; ks < 4; ks++) {
        bf16x8 bw = *(const bf16x8*)&wfr[((40 + (ct << 2) + ks) * 64 + l) * 8];
        acc2[ct] = __builtin_amdgcn_mfma_f32_16x16x32_bf16(ahm[ks], bw, acc2[ct], 0, 0, 0);
      }
    // tokens (bf16) -> stb [64 g][72], then emit deslice A-frags directly
#pragma unroll
    for (int ct = 0; ct < 4; ct++) {
      float bv = bm2[(ct << 4) + fr];
#pragma unroll
      for (int rr = 0; rr < 4; rr++)
        stb[(orow + rr) * 72 + (ct << 4) + fr] =
            f2b(acc2[ct][rr] + bv + o16[ct][rr]);
    }
  }
  __syncthreads();
  {
    // frag fid = w*2+e: mt=w, ks=e; lane l: elem j = tokens[g0+j][d]
#pragma unroll
    for (int e = 0; e < 2; e++) {
      int fid = (w << 1) + e;
      int d = (w << 4) + (l & 15);
      int g0 = (e << 5) + ((l >> 4) << 3);
      unsigned short v[8];
#pragma unroll
      for (int j = 0; j < 8; j++) v[j] = stb[(g0 + j) * 72 + d];
      unsigned short* op = wtokf + (((size_t)bh << 3) + fid) * 512 + (l << 3);
      *(u16x4*)op = *(u16x4*)v;
      *(u16x4*)(op + 4) = *(u16x4*)(v + 4);
    }
  }
}

// ---------------------------------------------------------------------------
// K8: deslice via MFMA, zero LDS (unchanged).
// ---------------------------------------------------------------------------
__global__ __launch_bounds__(256) void deslice_mfma(
    const unsigned short* __restrict__ wtokf, const unsigned short* __restrict__ sw,
    unsigned short* __restrict__ outx) {
  int bid = blockIdx.x;
  int bh = bid >> 4, c = bid & 15;
  int b = bh >> 3, h = bh & 7;
  int t = threadIdx.x, w = t >> 6, l = t & 63;
  const int fr = l & 15, fq = l >> 4;

  bf16x8 ta[4][2];
  const unsigned short* fp = wtokf + ((size_t)bh << 12);
#pragma unroll
  for (int mt = 0; mt < 4; mt++)
#pragma unroll
    for (int ks = 0; ks < 2; ks++)
      ta[mt][ks] = *(const bf16x8*)(fp + (((mt << 1) + ks) << 9) + (l << 3));

  int n0 = (c << 9) + (w << 7);
#pragma unroll 2
  for (int ntile = 0; ntile < 8; ntile++) {
    int nb = n0 + (ntile << 4);
    size_t rowb = ((size_t)(b * N_ + nb + fr) * 8 + h) << 6;
    bf16x8 b0 = *(const bf16x8*)(sw + rowb + (fq << 3));
    bf16x8 b1 = *(const bf16x8*)(sw + rowb + 32 + (fq << 3));
    f32x4 acc[4];
#pragma unroll
    for (int mt = 0; mt < 4; mt++) acc[mt] = (f32x4){0.f, 0.f, 0.f, 0.f};
#pragma unroll
    for (int mt = 0; mt < 4; mt++) {
      acc[mt] = __builtin_amdgcn_mfma_f32_16x16x32_bf16(ta[mt][0], b0, acc[mt], 0, 0, 0);
      acc[mt] = __builtin_amdgcn_mfma_f32_16x16x32_bf16(ta[mt][1], b1, acc[mt], 0, 0, 0);
    }
    unsigned short* op = outx + rowb + (fq << 2);
#pragma unroll
    for (int mt = 0; mt < 4; mt++) {
      u16x4 pk;
      pk.x = f2b(acc[mt][0]);
      pk.y = f2b(acc[mt][1]);
      pk.z = f2b(acc[mt][2]);
      pk.w = f2b(acc[mt][3]);
      *(u16x4*)(op + (mt << 4)) = pk;
    }
  }
}

// ---------------------------------------------------------------------------
extern "C" void kernel_launch(void* const* d_in, const int* in_sizes, int n_in,
                              void* d_out, int out_size, void* d_ws,
                              size_t ws_size, hipStream_t stream) {
  const float* fx = (const float*)d_in[0];
  const float* ln1g = (const float*)d_in[1];
  const float* ln1b = (const float*)d_in[2];
  const float* Wx = (const float*)d_in[3];
  const float* bx = (const float*)d_in[4];
  const float* Wfx = (const float*)d_in[5];
  const float* bfx = (const float*)d_in[6];
  const float* Wsl = (const float*)d_in[7];
  const float* bsl = (const float*)d_in[8];
  const float* temp = (const float*)d_in[9];
  const float* Wq = (const float*)d_in[10];
  const float* Wk = (const float*)d_in[11];
  const float* Wv = (const float*)d_in[12];
  const float* Wout = (const float*)d_in[13];
  const float* bout = (const float*)d_in[14];
  const float* tlng = (const float*)d_in[15];
  const float* tlnb = (const float*)d_in[16];
  const float* Wm1 = (const float*)d_in[17];
  const float* bm1 = (const float*)d_in[18];
  const float* Wm2 = (const float*)d_in[19];
  const float* bm2 = (const float*)d_in[20];
  float* out = (float*)d_out;

  char* p = (char*)d_ws;
  const size_t MC2 = (size_t)M_ * 512 * 2;
  unsigned short* fxn = (unsigned short*)p;  p += MC2;
  unsigned short* buf1 = (unsigned short*)p; p += MC2;  // x_mid -> slice_w
  unsigned short* bufT = (unsigned short*)p; p += MC2;  // fxT -> out_x
  unsigned short* WtX = (unsigned short*)p;  p += 512 * 512 * 2;
  unsigned short* WtF = (unsigned short*)p;  p += 512 * 512 * 2;
  unsigned short* WtO = (unsigned short*)p;  p += 512 * 512 * 2;
  unsigned short* wsf = (unsigned short*)p;  p += 8192;
  unsigned short* wfr = (unsigned short*)p;  p += 56 * 512 * 2;
  unsigned short* wtokf = (unsigned short*)p; p += (size_t)32 * 8 * 512 * 2;
  float* tok_part = (float*)p;  p += (size_t)512 * 4096 * 4;
  float* norm_part = (float*)p; p += (size_t)512 * 64 * 4;
  float* stG = (float*)p;       p += (size_t)32 * 4096 * 4;

  ln_bf16<<<M_ / 4, 256, 0, stream>>>(fx, ln1g, ln1b, fxn);
  prep_all<<<193, 256, 0, stream>>>(Wx, Wfx, Wout, Wsl, Wq, Wk, Wv, Wm1, Wm2,
                                    WtX, WtF, WtO, wsf, wfr);
  gemm_bf16<0, false, true, false><<<1024, 256, 0, stream>>>(fxn, WtX, bx, nullptr, buf1, 512);
  gemm_bf16<1, true, true, false><<<1024, 256, 0, stream>>>(WtF, fxn, bfx, nullptr, bufT, 32768);
  slice_mfma<<<4096, 256, 0, stream>>>(buf1, wsf, bsl, temp);
  pool_mfma<<<512, 256, 0, stream>>>(buf1, bufT, tok_part, norm_part);
  tok_reduce<<<128, 256, 0, stream>>>(tok_part, norm_part, stG);
  token_mfma<<<32, 256, 0, stream>>>(stG, wfr, tlng, tlnb, bm1, bm2, wtokf);
  deslice_mfma<<<512, 256, 0, stream>>>(wtokf, buf1, bufT);
  gemm_bf16<0, false, false, true><<<1024, 256, 0, stream>>>(bufT, WtO, bout, fxn, out, 512);
}

// Round 10
// 171.794 us; speedup vs baseline: 1.0784x; 1.0044x over previous
//
#include <hip/hip_runtime.h>
#include <math.h>

#define B_ 4
#define N_ 8192
#define C_ 512
#define H_ 8
#define M_ (B_ * N_) /* 32768 */

typedef __attribute__((ext_vector_type(8))) short bf16x8;
typedef __attribute__((ext_vector_type(4))) float f32x4;
typedef __attribute__((ext_vector_type(8))) unsigned short u16x8;
typedef __attribute__((ext_vector_type(4))) unsigned short u16x4;

__device__ __forceinline__ float b2f(unsigned short u) {
  union { unsigned int i; float f; } v;
  v.i = ((unsigned int)u) << 16;
  return v.f;
}
__device__ __forceinline__ unsigned short f2b(float f) {
  union { float f; unsigned int i; } v;
  v.f = f;
  unsigned int r = v.i + 0x7fff + ((v.i >> 16) & 1);
  return (unsigned short)(r >> 16);
}
__device__ __forceinline__ void gl_lds16(const void* g, void* l) {
  __builtin_amdgcn_global_load_lds(
      (const __attribute__((address_space(1))) unsigned int*)g,
      (__attribute__((address_space(3))) unsigned int*)l, 16, 0, 0);
}

// ---------------------------------------------------------------------------
// K1: LayerNorm over C=512 -> bf16. One wave per row.
// ---------------------------------------------------------------------------
__global__ __launch_bounds__(256) void ln_bf16(
    const float* __restrict__ x, const float* __restrict__ gam,
    const float* __restrict__ bet, unsigned short* __restrict__ y) {
  int wave = threadIdx.x >> 6, lane = threadIdx.x & 63;
  int row = (blockIdx.x << 2) + wave;
  const float4* xr = (const float4*)(x + (size_t)row * C_);
  float4 v0 = xr[lane], v1 = xr[lane + 64];
  float s = v0.x + v0.y + v0.z + v0.w + v1.x + v1.y + v1.z + v1.w;
  float q = v0.x * v0.x + v0.y * v0.y + v0.z * v0.z + v0.w * v0.w +
            v1.x * v1.x + v1.y * v1.y + v1.z * v1.z + v1.w * v1.w;
#pragma unroll
  for (int off = 32; off; off >>= 1) {
    s += __shfl_xor(s, off);
    q += __shfl_xor(q, off);
  }
  float mean = s * (1.0f / C_);
  float var = q * (1.0f / C_) - mean * mean;
  float rstd = rsqrtf(var + 1e-5f);
  const float4* gr = (const float4*)gam;
  const float4* br = (const float4*)bet;
  float4 g0 = gr[lane], g1 = gr[lane + 64];
  float4 b0 = br[lane], b1 = br[lane + 64];
  u16x4 oa, ob;
  oa.x = f2b((v0.x - mean) * rstd * g0.x + b0.x);
  oa.y = f2b((v0.y - mean) * rstd * g0.y + b0.y);
  oa.z = f2b((v0.z - mean) * rstd * g0.z + b0.z);
  oa.w = f2b((v0.w - mean) * rstd * g0.w + b0.w);
  ob.x = f2b((v1.x - mean) * rstd * g1.x + b1.x);
  ob.y = f2b((v1.y - mean) * rstd * g1.y + b1.y);
  ob.z = f2b((v1.z - mean) * rstd * g1.z + b1.z);
  ob.w = f2b((v1.w - mean) * rstd * g1.w + b1.w);
  unsigned short* yr = y + (size_t)row * C_;
  *(u16x4*)(yr + (lane << 2)) = oa;
  *(u16x4*)(yr + 256 + (lane << 2)) = ob;
}

// ---------------------------------------------------------------------------
// K2: merged prep (weight transposes + frag precomputes).
// ---------------------------------------------------------------------------
__global__ __launch_bounds__(256) void prep_all(
    const float* __restrict__ Wx, const float* __restrict__ Wfx,
    const float* __restrict__ Wout, const float* __restrict__ Wsl,
    const float* __restrict__ Wq, const float* __restrict__ Wk,
    const float* __restrict__ Wv, const float* __restrict__ Wm1,
    const float* __restrict__ Wm2, unsigned short* __restrict__ WtX,
    unsigned short* __restrict__ WtF, unsigned short* __restrict__ WtO,
    unsigned short* __restrict__ wsf, unsigned short* __restrict__ wfr) {
  __shared__ float tile[64][65];
  int blk = blockIdx.x, t = threadIdx.x;
  if (blk < 192) {
    int which = blk >> 6, sub = blk & 63;
    const float* W = (which == 0) ? Wx : (which == 1) ? Wfx : Wout;
    unsigned short* Wt = (which == 0) ? WtX : (which == 1) ? WtF : WtO;
    int r0 = (sub >> 3) << 6, c0 = (sub & 7) << 6;
    int lr = t >> 4, lc = (t & 15) << 2;
#pragma unroll
    for (int p = 0; p < 4; p++) {
      float4 v = *(const float4*)(W + (size_t)(r0 + lr + p * 16) * 512 + c0 + lc);
      tile[lr + p * 16][lc + 0] = v.x;
      tile[lr + p * 16][lc + 1] = v.y;
      tile[lr + p * 16][lc + 2] = v.z;
      tile[lr + p * 16][lc + 3] = v.w;
    }
    __syncthreads();
    int on = t >> 2, ok = (t & 3) << 4;
    unsigned short tmp[16];
#pragma unroll
    for (int j = 0; j < 16; j++) tmp[j] = f2b(tile[ok + j][on]);
    unsigned short* op = Wt + (size_t)(c0 + on) * 512 + r0 + ok;
#pragma unroll
    for (int j4 = 0; j4 < 4; j4++)
      *(u16x4*)(op + (j4 << 2)) = *(u16x4*)(tmp + (j4 << 2));
  } else {
#pragma unroll
    for (int i = 0; i < 2; i++) {
      int idx = t + i * 256;
      int f = idx >> 6, l = idx & 63;
      int gt = f >> 1, ks = f & 1;
      int g = (gt << 4) + (l & 15);
      int d0 = (ks << 5) + ((l >> 4) << 3);
      unsigned short v[8];
#pragma unroll
      for (int jj = 0; jj < 8; jj++) v[jj] = f2b(Wsl[(size_t)(d0 + jj) * 64 + g]);
      *(u16x4*)(wsf + idx * 8) = *(u16x4*)v;
      *(u16x4*)(wsf + idx * 8 + 4) = *(u16x4*)(v + 4);
    }
    for (int task = t; task < 56 * 64; task += 256) {
      int fid = task >> 6, l = task & 63;
      const float* W;
      int stride, ct, ks;
      if (fid < 24) {
        W = (fid < 8) ? Wq : (fid < 16) ? Wk : Wv;
        int e = fid & 7;
        ct = e >> 1;
        ks = e & 1;
        stride = 64;
      } else if (fid < 40) {
        W = Wm1;
        int e = fid - 24;
        ct = e >> 1;
        ks = e & 1;
        stride = 128;
      } else {
        W = Wm2;
        int e = fid - 40;
        ct = e >> 2;
        ks = e & 3;
        stride = 64;
      }
      int d0 = (ks << 5) + ((l >> 4) << 3);
      int c = (ct << 4) + (l & 15);
      unsigned short v[8];
#pragma unroll
      for (int j = 0; j < 8; j++) v[j] = f2b(W[(size_t)(d0 + j) * stride + c]);
      *(u16x4*)(wfr + task * 8) = *(u16x4*)v;
      *(u16x4*)(wfr + task * 8 + 4) = *(u16x4*)(v + 4);
    }
  }
}

// ---------------------------------------------------------------------------
// K4: bf16 MFMA GEMM, single-buffer, BK=64 (unchanged from round 9).
// ---------------------------------------------------------------------------
template <int DEC, bool BIASROW, bool OUTBF, bool RES>
__global__ __launch_bounds__(256) void gemm_bf16(
    const unsigned short* __restrict__ A, const unsigned short* __restrict__ Bt,
    const float* __restrict__ bias, const unsigned short* __restrict__ resid,
    void* __restrict__ Cout, size_t ldC) {
  __shared__ unsigned short lds[16384];
  const int t = threadIdx.x;
  const int w = t >> 6, l = t & 63;
  int bid = blockIdx.x;
  int xcd = bid & 7, q = bid >> 3;
  int bm, bn;
  if (DEC == 0) {
    bm = ((xcd << 5) + (q >> 2)) << 7;
    bn = (q & 3) << 7;
  } else {
    bn = ((xcd << 5) + (q >> 2)) << 7;
    bm = (q & 3) << 7;
  }
  const int wm = (w >> 1) << 6, wn = (w & 1) << 6;
  f32x4 acc[4][4];
#pragma unroll
  for (int mt = 0; mt < 4; mt++)
#pragma unroll
    for (int nt = 0; nt < 4; nt++) acc[mt][nt] = (f32x4){0.f, 0.f, 0.f, 0.f};

  const int srow = t >> 3;
  const int scol = (((t & 7) ^ ((t >> 3) & 7)) << 3);
  const unsigned short* gA = A + (size_t)(bm + srow) * 512 + scol;
  const unsigned short* gB = Bt + (size_t)(bn + srow) * 512 + scol;
  const int fr = l & 15, qq = l >> 4;

  for (int k0 = 0; k0 < 512; k0 += 64) {
#pragma unroll
    for (int i = 0; i < 4; i++)
      gl_lds16(gA + (size_t)(i << 5) * 512 + k0, lds + (i << 11) + (w << 9));
#pragma unroll
    for (int i = 0; i < 4; i++)
      gl_lds16(gB + (size_t)(i << 5) * 512 + k0, lds + 8192 + (i << 11) + (w << 9));
    __syncthreads();
#pragma unroll
    for (int kk = 0; kk < 2; kk++) {
      bf16x8 af[4], bfr[4];
#pragma unroll
      for (int mt = 0; mt < 4; mt++) {
        int row = wm + mt * 16 + fr;
        af[mt] = *(const bf16x8*)&lds[row * 64 + ((((kk << 2) + qq) ^ (fr & 7)) << 3)];
      }
#pragma unroll
      for (int nt = 0; nt < 4; nt++) {
        int row = wn + nt * 16 + fr;
        bfr[nt] = *(const bf16x8*)&lds[8192 + row * 64 + ((((kk << 2) + qq) ^ (fr & 7)) << 3)];
      }
#pragma unroll
      for (int mt = 0; mt < 4; mt++)
#pragma unroll
        for (int nt = 0; nt < 4; nt++)
          acc[mt][nt] = __builtin_amdgcn_mfma_f32_16x16x32_bf16(
              af[mt], bfr[nt], acc[mt][nt], 0, 0, 0);
    }
    __syncthreads();
  }

  const int col0 = bn + wn + (l & 15);
  const int row0 = bm + wm + ((l >> 4) << 2);
#pragma unroll
  for (int mt = 0; mt < 4; mt++) {
#pragma unroll
    for (int j = 0; j < 4; j++) {
      int row = row0 + mt * 16 + j;
#pragma unroll
      for (int nt = 0; nt < 4; nt++) {
        int col = col0 + nt * 16;
        float v = acc[mt][nt][j] + (BIASROW ? bias[row] : bias[col]);
        if (RES) v += b2f(resid[(size_t)row * ldC + col]);
        if (OUTBF)
          ((unsigned short*)Cout)[(size_t)row * ldC + col] = f2b(v);
        else
          ((float*)Cout)[(size_t)row * ldC + col] = v;
      }
    }
  }
}

// ---------------------------------------------------------------------------
// K6: pool + INLINE slice softmax. Per 64-row chunk: x_mid B-frags ->
// logits MFMA -> softmax (regs) -> scatter P into swizzled wT -> pool MFMA.
// slice_w never touches global memory.
// ---------------------------------------------------------------------------
__global__ __launch_bounds__(256) void pool_mfma(
    const unsigned short* __restrict__ xmid, const unsigned short* __restrict__ fxT,
    const unsigned short* __restrict__ wf, const float* __restrict__ bslice,
    const float* __restrict__ temp, float* __restrict__ tok_part,
    float* __restrict__ norm_part) {
  __shared__ unsigned short wT[4096];
  int bid = blockIdx.x;
  int bh = bid >> 4, c = bid & 15;
  int b = bh >> 3, h = bh & 7;
  int t = threadIdx.x, w = t >> 6, l = t & 63;
  int n0 = c << 9;
  const int fr15 = l & 15, fs = l >> 4;

  bf16x8 wsf[4][2];
#pragma unroll
  for (int gt = 0; gt < 4; gt++)
#pragma unroll
    for (int ks = 0; ks < 2; ks++)
      wsf[gt][ks] = *(const bf16x8*)(wf + (((gt << 1) + ks) * 64 + l) * 8);
  float invt = 1.0f / temp[h];
  float bsl16[16];
#pragma unroll
  for (int gt = 0; gt < 4; gt++)
#pragma unroll
    for (int r = 0; r < 4; r++)
      bsl16[(gt << 2) + r] = bslice[(gt << 4) + (fs << 2) + r];

  f32x4 acc[4];
#pragma unroll
  for (int gt = 0; gt < 4; gt++) acc[gt] = (f32x4){0.f, 0.f, 0.f, 0.f};
  float nacc[4] = {0.f, 0.f, 0.f, 0.f};

  const unsigned short* fxrow =
      fxT + (size_t)(h * 64 + w * 16 + fr15) * 32768 + b * N_ + n0 + (fs << 3);
  const int ncol = (w << 4) + fr15;  // this lane's row within the 64-chunk

  for (int nn = 0; nn < 512; nn += 64) {
    // ---- inline slice: logits + softmax for row (n0+nn+ncol, h) ----
    size_t xrow = ((size_t)(b * N_ + n0 + nn + ncol) * 8 + h) << 6;
    bf16x8 xf0 = *(const bf16x8*)(xmid + xrow + (fs << 3));
    bf16x8 xf1 = *(const bf16x8*)(xmid + xrow + 32 + (fs << 3));
    f32x4 lg4[4];
#pragma unroll
    for (int gt = 0; gt < 4; gt++) {
      lg4[gt] = (f32x4){0.f, 0.f, 0.f, 0.f};
      lg4[gt] = __builtin_amdgcn_mfma_f32_16x16x32_bf16(wsf[gt][0], xf0, lg4[gt], 0, 0, 0);
      lg4[gt] = __builtin_amdgcn_mfma_f32_16x16x32_bf16(wsf[gt][1], xf1, lg4[gt], 0, 0, 0);
    }
    float p[16];
    float mx = -1e30f;
#pragma unroll
    for (int gt = 0; gt < 4; gt++)
#pragma unroll
      for (int r = 0; r < 4; r++) {
        float v = (lg4[gt][r] + bsl16[(gt << 2) + r]) * invt;
        p[(gt << 2) + r] = v;
        mx = fmaxf(mx, v);
      }
    mx = fmaxf(mx, __shfl_xor(mx, 16));
    mx = fmaxf(mx, __shfl_xor(mx, 32));
    float ssum = 0.f;
#pragma unroll
    for (int i = 0; i < 16; i++) {
      p[i] = expf(p[i] - mx);
      ssum += p[i];
    }
    ssum += __shfl_xor(ssum, 16);
    ssum += __shfl_xor(ssum, 32);
    float inv = 1.0f / ssum;
    __syncthreads();  // prior frag reads done before overwrite
#pragma unroll
    for (int gt = 0; gt < 4; gt++)
#pragma unroll
      for (int r = 0; r < 4; r++) {
        int g = (gt << 4) + (fs << 2) + r;
        wT[(g << 6) + ((((ncol >> 3)) ^ (g & 7)) << 3) + (ncol & 7)] =
            f2b(p[(gt << 2) + r] * inv);
      }
    __syncthreads();
    // ---- pool MFMA ----
#pragma unroll
    for (int kk = 0; kk < 2; kk++) {
      bf16x8 bfrag = *(const bf16x8*)(fxrow + nn + (kk << 5));
#pragma unroll
      for (int gt = 0; gt < 4; gt++) {
        int g = (gt << 4) + fr15;
        int slot = (kk << 2) + fs;
        bf16x8 af = *(const bf16x8*)&wT[(g << 6) + ((slot ^ (g & 7)) << 3)];
        acc[gt] = __builtin_amdgcn_mfma_f32_16x16x32_bf16(af, bfrag, acc[gt], 0, 0, 0);
        if (w == 0) {
#pragma unroll
          for (int j = 0; j < 8; j++) nacc[gt] += b2f((unsigned short)af[j]);
        }
      }
    }
  }
  float* op = tok_part + ((size_t)bid << 12);
#pragma unroll
  for (int gt = 0; gt < 4; gt++)
#pragma unroll
    for (int rr = 0; rr < 4; rr++)
      op[((gt << 4) + (fs << 2) + rr) * 64 + (w << 4) + fr15] = acc[gt][rr];
  if (w == 0) {
#pragma unroll
    for (int gt = 0; gt < 4; gt++) {
      float s = nacc[gt];
      s += __shfl_xor(s, 16);
      s += __shfl_xor(s, 32);
      if (l < 16) norm_part[(bid << 6) + (gt << 4) + l] = s;
    }
  }
}

// ---------------------------------------------------------------------------
// K7: token pipeline via MFMA + fused tok_part reduce + deslice-frag emit.
// ---------------------------------------------------------------------------
__device__ __forceinline__ float gelu_exact(float x) {
  return 0.5f * x * (1.0f + erff(x * 0.70710678118654752f));
}

__global__ __launch_bounds__(256) void token_mfma(
    const float* __restrict__ tok_part, const float* __restrict__ norm_part,
    const unsigned short* __restrict__ wfr, const float* __restrict__ tg,
    const float* __restrict__ tb, const float* __restrict__ bm1,
    const float* __restrict__ bm2, unsigned short* __restrict__ wtokf) {
  __shared__ __align__(16) char smem[54272];
  __shared__ float red[64];
  unsigned short* stb = (unsigned short*)smem;
  float* st32 = (float*)(smem + 9216);
  unsigned short* hmld = (unsigned short*)(smem + 9216);
  unsigned short* qld = (unsigned short*)(smem + 26624);
  unsigned short* kld = (unsigned short*)(smem + 35840);
  unsigned short* vtl = (unsigned short*)(smem + 45056);

  int bh = blockIdx.x, t = threadIdx.x, w = t >> 6, l = t & 63;
  const int fr = l & 15, fq = l >> 4;

  // ---- fused reduce of tok_part + norm_part -> slice_tok ----
  if (t < 64) {
    float s = 0.f;
    const float* np = norm_part + ((size_t)bh << 10);
#pragma unroll
    for (int cc = 0; cc < 16; cc++) s += np[(cc << 6) + t];
    red[t] = s;
  }
  {
    float a16[16];
#pragma unroll
    for (int j = 0; j < 16; j++) a16[j] = 0.f;
    const float* tp = tok_part + ((size_t)bh << 16) + (t << 4);
    for (int cc = 0; cc < 16; cc++) {
      const float* pp = tp + (cc << 12);
#pragma unroll
      for (int j4 = 0; j4 < 4; j4++) {
        float4 v = *(const float4*)(pp + (j4 << 2));
        a16[j4 * 4 + 0] += v.x;
        a16[j4 * 4 + 1] += v.y;
        a16[j4 * 4 + 2] += v.z;
        a16[j4 * 4 + 3] += v.w;
      }
    }
    __syncthreads();
    float rn = 1.0f / (red[t >> 2] + 1e-5f);
    int r = t >> 2, c0 = (t & 3) << 4;
    unsigned short tv[16];
#pragma unroll
    for (int j = 0; j < 16; j++) {
      float v = a16[j] * rn;
      st32[r * 68 + c0 + j] = v;
      tv[j] = f2b(v);
    }
    *(u16x8*)&stb[r * 72 + c0] = *(u16x8*)tv;
    *(u16x8*)&stb[r * 72 + c0 + 8] = *(u16x8*)(tv + 8);
  }
  __syncthreads();

  const int orow = (w << 4) + (fq << 2);

  {
    bf16x8 af[2];
#pragma unroll
    for (int ks = 0; ks < 2; ks++)
      af[ks] = *(const bf16x8*)&stb[((w << 4) + fr) * 72 + (ks << 5) + (fq << 3)];
    f32x4 aq[4], ak[4], av[4];
#pragma unroll
    for (int ct = 0; ct < 4; ct++) {
      aq[ct] = (f32x4){0.f, 0.f, 0.f, 0.f};
      ak[ct] = (f32x4){0.f, 0.f, 0.f, 0.f};
      av[ct] = (f32x4){0.f, 0.f, 0.f, 0.f};
    }
#pragma unroll
    for (int ct = 0; ct < 4; ct++)
#pragma unroll
      for (int ks = 0; ks < 2; ks++) {
        bf16x8 bq = *(const bf16x8*)&wfr[(((ct << 1) + ks) * 64 + l) * 8];
        aq[ct] = __builtin_amdgcn_mfma_f32_16x16x32_bf16(af[ks], bq, aq[ct], 0, 0, 0);
      }
#pragma unroll
    for (int ct = 0; ct < 4; ct++)
#pragma unroll
      for (int ks = 0; ks < 2; ks++) {
        bf16x8 bk = *(const bf16x8*)&wfr[((8 + (ct << 1) + ks) * 64 + l) * 8];
        ak[ct] = __builtin_amdgcn_mfma_f32_16x16x32_bf16(af[ks], bk, ak[ct], 0, 0, 0);
      }
#pragma unroll
    for (int ct = 0; ct < 4; ct++)
#pragma unroll
      for (int ks = 0; ks < 2; ks++) {
        bf16x8 bv = *(const bf16x8*)&wfr[((16 + (ct << 1) + ks) * 64 + l) * 8];
        av[ct] = __builtin_amdgcn_mfma_f32_16x16x32_bf16(af[ks], bv, av[ct], 0, 0, 0);
      }
#pragma unroll
    for (int ct = 0; ct < 4; ct++) {
#pragma unroll
      for (int rr = 0; rr < 4; rr++) {
        qld[(orow + rr) * 72 + (ct << 4) + fr] = f2b(aq[ct][rr]);
        kld[(orow + rr) * 72 + (ct << 4) + fr] = f2b(ak[ct][rr]);
      }
      u16x4 vp;
      vp.x = f2b(av[ct][0]);
      vp.y = f2b(av[ct][1]);
      vp.z = f2b(av[ct][2]);
      vp.w = f2b(av[ct][3]);
      *(u16x4*)&vtl[((ct << 4) + fr) * 72 + orow] = vp;
    }
  }
  __syncthreads();

  {
    bf16x8 aq[2];
#pragma unroll
    for (int ks = 0; ks < 2; ks++)
      aq[ks] = *(const bf16x8*)&qld[((w << 4) + fr) * 72 + (ks << 5) + (fq << 3)];
    f32x4 accs[4];
#pragma unroll
    for (int nt = 0; nt < 4; nt++) accs[nt] = (f32x4){0.f, 0.f, 0.f, 0.f};
#pragma unroll
    for (int nt = 0; nt < 4; nt++)
#pragma unroll
      for (int ks = 0; ks < 2; ks++) {
        bf16x8 bk = *(const bf16x8*)&kld[((nt << 4) + fr) * 72 + (ks << 5) + (fq << 3)];
        accs[nt] = __builtin_amdgcn_mfma_f32_16x16x32_bf16(aq[ks], bk, accs[nt], 0, 0, 0);
      }
#pragma unroll
    for (int rr = 0; rr < 4; rr++) {
      float v0 = accs[0][rr] * 0.125f, v1 = accs[1][rr] * 0.125f;
      float v2 = accs[2][rr] * 0.125f, v3 = accs[3][rr] * 0.125f;
      float mx = fmaxf(fmaxf(v0, v1), fmaxf(v2, v3));
      mx = fmaxf(mx, __shfl_xor(mx, 1));
      mx = fmaxf(mx, __shfl_xor(mx, 2));
      mx = fmaxf(mx, __shfl_xor(mx, 4));
      mx = fmaxf(mx, __shfl_xor(mx, 8));
      float e0 = expf(v0 - mx), e1 = expf(v1 - mx);
      float e2 = expf(v2 - mx), e3 = expf(v3 - mx);
      float ss = e0 + e1 + e2 + e3;
      ss += __shfl_xor(ss, 1);
      ss += __shfl_xor(ss, 2);
      ss += __shfl_xor(ss, 4);
      ss += __shfl_xor(ss, 8);
      float inv = 1.0f / ss;
      stb[(orow + rr) * 72 + 0 * 16 + fr] = f2b(e0 * inv);
      stb[(orow + rr) * 72 + 1 * 16 + fr] = f2b(e1 * inv);
      stb[(orow + rr) * 72 + 2 * 16 + fr] = f2b(e2 * inv);
      stb[(orow + rr) * 72 + 3 * 16 + fr] = f2b(e3 * inv);
    }
  }
  __syncthreads();

  float o16[4][4];
  {
    bf16x8 ap[2];
#pragma unroll
    for (int ks = 0; ks < 2; ks++)
      ap[ks] = *(const bf16x8*)&stb[((w << 4) + fr) * 72 + (ks << 5) + (fq << 3)];
    f32x4 acco[4];
#pragma unroll
    for (int ct = 0; ct < 4; ct++) acco[ct] = (f32x4){0.f, 0.f, 0.f, 0.f};
#pragma unroll
    for (int ct = 0; ct < 4; ct++)
#pragma unroll
      for (int ks = 0; ks < 2; ks++) {
        bf16x8 bv = *(const bf16x8*)&vtl[((ct << 4) + fr) * 72 + (ks << 5) + (fq << 3)];
        acco[ct] = __builtin_amdgcn_mfma_f32_16x16x32_bf16(ap[ks], bv, acco[ct], 0, 0, 0);
      }
    float tgv[4], tbv[4];
#pragma unroll
    for (int ct = 0; ct < 4; ct++) {
      tgv[ct] = tg[(ct << 4) + fr];
      tbv[ct] = tb[(ct << 4) + fr];
    }
#pragma unroll
    for (int ct = 0; ct < 4; ct++)
#pragma unroll
      for (int rr = 0; rr < 4; rr++)
        o16[ct][rr] = acco[ct][rr] + st32[(orow + rr) * 68 + (ct << 4) + fr];
#pragma unroll
    for (int rr = 0; rr < 4; rr++) {
      float sm = o16[0][rr] + o16[1][rr] + o16[2][rr] + o16[3][rr];
      float sq = o16[0][rr] * o16[0][rr] + o16[1][rr] * o16[1][rr] +
                 o16[2][rr] * o16[2][rr] + o16[3][rr] * o16[3][rr];
      sm += __shfl_xor(sm, 1);
      sm += __shfl_xor(sm, 2);
      sm += __shfl_xor(sm, 4);
      sm += __shfl_xor(sm, 8);
      sq += __shfl_xor(sq, 1);
      sq += __shfl_xor(sq, 2);
      sq += __shfl_xor(sq, 4);
      sq += __shfl_xor(sq, 8);
      float mean = sm * (1.0f / 64.0f);
      float var = sq * (1.0f / 64.0f) - mean * mean;
      float rstd = rsqrtf(var + 1e-5f);
#pragma unroll
      for (int ct = 0; ct < 4; ct++) {
        float hv = (o16[ct][rr] - mean) * rstd * tgv[ct] + tbv[ct];
        qld[(orow + rr) * 72 + (ct << 4) + fr] = f2b(hv);
      }
    }
  }
  __syncthreads();

  {
    bf16x8 ah[2];
#pragma unroll
    for (int ks = 0; ks < 2; ks++)
      ah[ks] = *(const bf16x8*)&qld[((w << 4) + fr) * 72 + (ks << 5) + (fq << 3)];
    f32x4 accm[8];
#pragma unroll
    for (int et = 0; et < 8; et++) accm[et] = (f32x4){0.f, 0.f, 0.f, 0.f};
#pragma unroll
    for (int et = 0; et < 8; et++)
#pragma unroll
      for (int ks = 0; ks < 2; ks++) {
        bf16x8 bm = *(const bf16x8*)&wfr[((24 + (et << 1) + ks) * 64 + l) * 8];
        accm[et] = __builtin_amdgcn_mfma_f32_16x16x32_bf16(ah[ks], bm, accm[et], 0, 0, 0);
      }
#pragma unroll
    for (int et = 0; et < 8; et++) {
      float bv = bm1[(et << 4) + fr];
#pragma unroll
      for (int rr = 0; rr < 4; rr++) {
        float x = accm[et][rr] + bv;
        hmld[(orow + rr) * 136 + (et << 4) + fr] = f2b(gelu_exact(x));
      }
    }
  }
  __syncthreads();

  {
    bf16x8 ahm[4];
#pragma unroll
    for (int ks = 0; ks < 4; ks++)
      ahm[ks] = *(const bf16x8*)&hmld[((w << 4) + fr) * 136 + (ks << 5) + (fq << 3)];
    f32x4 acc2[4];
#pragma unroll
    for (int ct = 0; ct < 4; ct++) acc2[ct] = (f32x4){0.f, 0.f, 0.f, 0.f};
#pragma unroll
    for (int ct = 0; ct < 4; ct++)
#pragma unroll
      for (int ks = 0; ks < 4; ks++) {
        bf16x8 bw = *(const bf16x8*)&wfr[((40 + (ct << 2) + ks) * 64 + l) * 8];
        acc2[ct] = __builtin_amdgcn_mfma_f32_16x16x32_bf16(ahm[ks], bw, acc2[ct], 0, 0, 0);
      }
#pragma unroll
    for (int ct = 0; ct < 4; ct++) {
      float bv = bm2[(ct << 4) + fr];
#pragma unroll
      for (int rr = 0; rr < 4; rr++)
        stb[(orow + rr) * 72 + (ct << 4) + fr] =
            f2b(acc2[ct][rr] + bv + o16[ct][rr]);
    }
  }
  __syncthreads();
  {
#pragma unroll
    for (int e = 0; e < 2; e++) {
      int fid = (w << 1) + e;
      int d = (w << 4) + (l & 15);
      int g0 = (e << 5) + ((l >> 4) << 3);
      unsigned short v[8];
#pragma unroll
      for (int j = 0; j < 8; j++) v[j] = stb[(g0 + j) * 72 + d];
      unsigned short* op = wtokf + (((size_t)bh << 3) + fid) * 512 + (l << 3);
      *(u16x4*)op = *(u16x4*)v;
      *(u16x4*)(op + 4) = *(u16x4*)(v + 4);
    }
  }
}

// ---------------------------------------------------------------------------
// K8: deslice + INLINE slice softmax. Per 16-row tile: x_mid B-frags ->
// logits MFMA -> softmax -> per-wave swizzled LDS exchange (wave-sync, no
// barriers) -> P B-frags -> PV MFMA -> store out_x.
// ---------------------------------------------------------------------------
__global__ __launch_bounds__(256) void deslice_mfma(
    const unsigned short* __restrict__ wtokf, const unsigned short* __restrict__ xmid,
    const unsigned short* __restrict__ wf, const float* __restrict__ bslice,
    const float* __restrict__ temp, unsigned short* __restrict__ outx) {
  __shared__ unsigned short pex[4][1024];  // per-wave [16][64] swizzled P
  int bid = blockIdx.x;
  int bh = bid >> 4, c = bid & 15;
  int b = bh >> 3, h = bh & 7;
  int t = threadIdx.x, w = t >> 6, l = t & 63;
  const int fr = l & 15, fq = l >> 4;
  unsigned short* pw = pex[w];

  bf16x8 ta[4][2];
  const unsigned short* fp = wtokf + ((size_t)bh << 12);
#pragma unroll
  for (int mt = 0; mt < 4; mt++)
#pragma unroll
    for (int ks = 0; ks < 2; ks++)
      ta[mt][ks] = *(const bf16x8*)(fp + (((mt << 1) + ks) << 9) + (l << 3));
  bf16x8 wsf[4][2];
#pragma unroll
  for (int gt = 0; gt < 4; gt++)
#pragma unroll
    for (int ks = 0; ks < 2; ks++)
      wsf[gt][ks] = *(const bf16x8*)(wf + (((gt << 1) + ks) * 64 + l) * 8);
  float invt = 1.0f / temp[h];
  float bsl16[16];
#pragma unroll
  for (int gt = 0; gt < 4; gt++)
#pragma unroll
    for (int r = 0; r < 4; r++)
      bsl16[(gt << 2) + r] = bslice[(gt << 4) + (fq << 2) + r];

  int n0 = (c << 9) + (w << 7);
  for (int ntile = 0; ntile < 8; ntile++) {
    int nb = n0 + (ntile << 4);
    size_t rowb = ((size_t)(b * N_ + nb + fr) * 8 + h) << 6;
    // ---- inline slice for rows nb..nb+15 ----
    bf16x8 xf0 = *(const bf16x8*)(xmid + rowb + (fq << 3));
    bf16x8 xf1 = *(const bf16x8*)(xmid + rowb + 32 + (fq << 3));
    f32x4 lg4[4];
#pragma unroll
    for (int gt = 0; gt < 4; gt++) {
      lg4[gt] = (f32x4){0.f, 0.f, 0.f, 0.f};
      lg4[gt] = __builtin_amdgcn_mfma_f32_16x16x32_bf16(wsf[gt][0], xf0, lg4[gt], 0, 0, 0);
      lg4[gt] = __builtin_amdgcn_mfma_f32_16x16x32_bf16(wsf[gt][1], xf1, lg4[gt], 0, 0, 0);
    }
    float p[16];
    float mx = -1e30f;
#pragma unroll
    for (int gt = 0; gt < 4; gt++)
#pragma unroll
      for (int r = 0; r < 4; r++) {
        float v = (lg4[gt][r] + bsl16[(gt << 2) + r]) * invt;
        p[(gt << 2) + r] = v;
        mx = fmaxf(mx, v);
      }
    mx = fmaxf(mx, __shfl_xor(mx, 16));
    mx = fmaxf(mx, __shfl_xor(mx, 32));
    float ssum = 0.f;
#pragma unroll
    for (int i = 0; i < 16; i++) {
      p[i] = expf(p[i] - mx);
      ssum += p[i];
    }
    ssum += __shfl_xor(ssum, 16);
    ssum += __shfl_xor(ssum, 32);
    float inv = 1.0f / ssum;
    // scatter P (row = fr, swizzled 8-slots) — wave-synchronous LDS
#pragma unroll
    for (int gt = 0; gt < 4; gt++)
#pragma unroll
      for (int r = 0; r < 4; r++) {
        int g = (gt << 4) + (fq << 2) + r;
        pw[(fr << 6) + (((g >> 3) ^ (fr & 7)) << 3) + (g & 7)] =
            f2b(p[(gt << 2) + r] * inv);
      }
    bf16x8 b0 = *(const bf16x8*)&pw[(fr << 6) + ((fq ^ (fr & 7)) << 3)];
    bf16x8 b1 = *(const bf16x8*)&pw[(fr << 6) + (((4 + fq) ^ (fr & 7)) << 3)];
    // ---- PV ----
    f32x4 acc[4];
#pragma unroll
    for (int mt = 0; mt < 4; mt++) acc[mt] = (f32x4){0.f, 0.f, 0.f, 0.f};
#pragma unroll
    for (int mt = 0; mt < 4; mt++) {
      acc[mt] = __builtin_amdgcn_mfma_f32_16x16x32_bf16(ta[mt][0], b0, acc[mt], 0, 0, 0);
      acc[mt] = __builtin_amdgcn_mfma_f32_16x16x32_bf16(ta[mt][1], b1, acc[mt], 0, 0, 0);
    }
    unsigned short* op = outx + rowb + (fq << 2);
#pragma unroll
    for (int mt = 0; mt < 4; mt++) {
      u16x4 pk;
      pk.x = f2b(acc[mt][0]);
      pk.y = f2b(acc[mt][1]);
      pk.z = f2b(acc[mt][2]);
      pk.w = f2b(acc[mt][3]);
      *(u16x4*)(op + (mt << 4)) = pk;
    }
  }
}

// ---------------------------------------------------------------------------
extern "C" void kernel_launch(void* const* d_in, const int* in_sizes, int n_in,
                              void* d_out, int out_size, void* d_ws,
                              size_t ws_size, hipStream_t stream) {
  const float* fx = (const float*)d_in[0];
  const float* ln1g = (const float*)d_in[1];
  const float* ln1b = (const float*)d_in[2];
  const float* Wx = (const float*)d_in[3];
  const float* bx = (const float*)d_in[4];
  const float* Wfx = (const float*)d_in[5];
  const float* bfx = (const float*)d_in[6];
  const float* Wsl = (const float*)d_in[7];
  const float* bsl = (const float*)d_in[8];
  const float* temp = (const float*)d_in[9];
  const float* Wq = (const float*)d_in[10];
  const float* Wk = (const float*)d_in[11];
  const float* Wv = (const float*)d_in[12];
  const float* Wout = (const float*)d_in[13];
  const float* bout = (const float*)d_in[14];
  const float* tlng = (const float*)d_in[15];
  const float* tlnb = (const float*)d_in[16];
  const float* Wm1 = (const float*)d_in[17];
  const float* bm1 = (const float*)d_in[18];
  const float* Wm2 = (const float*)d_in[19];
  const float* bm2 = (const float*)d_in[20];
  float* out = (float*)d_out;

  char* p = (char*)d_ws;
  const size_t MC2 = (size_t)M_ * 512 * 2;
  unsigned short* fxn = (unsigned short*)p;  p += MC2;
  unsigned short* buf1 = (unsigned short*)p; p += MC2;  // x_mid (stays)
  unsigned short* bufT = (unsigned short*)p; p += MC2;  // fxT -> out_x
  unsigned short* WtX = (unsigned short*)p;  p += 512 * 512 * 2;
  unsigned short* WtF = (unsigned short*)p;  p += 512 * 512 * 2;
  unsigned short* WtO = (unsigned short*)p;  p += 512 * 512 * 2;
  unsigned short* wsf = (unsigned short*)p;  p += 8192;
  unsigned short* wfr = (unsigned short*)p;  p += 56 * 512 * 2;
  unsigned short* wtokf = (unsigned short*)p; p += (size_t)32 * 8 * 512 * 2;
  float* tok_part = (float*)p;  p += (size_t)512 * 4096 * 4;
  float* norm_part = (float*)p; p += (size_t)512 * 64 * 4;

  ln_bf16<<<M_ / 4, 256, 0, stream>>>(fx, ln1g, ln1b, fxn);
  prep_all<<<193, 256, 0, stream>>>(Wx, Wfx, Wout, Wsl, Wq, Wk, Wv, Wm1, Wm2,
                                    WtX, WtF, WtO, wsf, wfr);
  gemm_bf16<0, false, true, false><<<1024, 256, 0, stream>>>(fxn, WtX, bx, nullptr, buf1, 512);
  gemm_bf16<1, true, true, false><<<1024, 256, 0, stream>>>(WtF, fxn, bfx, nullptr, bufT, 32768);
  pool_mfma<<<512, 256, 0, stream>>>(buf1, bufT, wsf, bsl, temp, tok_part, norm_part);
  token_mfma<<<32, 256, 0, stream>>>(tok_part, norm_part, wfr, tlng, tlnb, bm1, bm2, wtokf);
  deslice_mfma<<<512, 256, 0, stream>>>(wtokf, buf1, wsf, bsl, temp, bufT);
  gemm_bf16<0, false, false, true><<<1024, 256, 0, stream>>>(bufT, WtO, bout, fxn, out, 512);
}

// Round 11
// 167.477 us; speedup vs baseline: 1.1062x; 1.0258x over previous
//
#include <hip/hip_runtime.h>
#include <math.h>

#define B_ 4
#define N_ 8192
#define C_ 512
#define H_ 8
#define M_ (B_ * N_) /* 32768 */

typedef __attribute__((ext_vector_type(8))) short bf16x8;
typedef __attribute__((ext_vector_type(4))) float f32x4;
typedef __attribute__((ext_vector_type(8))) unsigned short u16x8;
typedef __attribute__((ext_vector_type(4))) unsigned short u16x4;

__device__ __forceinline__ float b2f(unsigned short u) {
  union { unsigned int i; float f; } v;
  v.i = ((unsigned int)u) << 16;
  return v.f;
}
__device__ __forceinline__ unsigned short f2b(float f) {
  union { float f; unsigned int i; } v;
  v.f = f;
  unsigned int r = v.i + 0x7fff + ((v.i >> 16) & 1);
  return (unsigned short)(r >> 16);
}
__device__ __forceinline__ void gl_lds16(const void* g, void* l) {
  __builtin_amdgcn_global_load_lds(
      (const __attribute__((address_space(1))) unsigned int*)g,
      (__attribute__((address_space(3))) unsigned int*)l, 16, 0, 0);
}

// ---------------------------------------------------------------------------
// K1: LayerNorm over C=512 -> bf16. One wave per row.
// ---------------------------------------------------------------------------
__global__ __launch_bounds__(256) void ln_bf16(
    const float* __restrict__ x, const float* __restrict__ gam,
    const float* __restrict__ bet, unsigned short* __restrict__ y) {
  int wave = threadIdx.x >> 6, lane = threadIdx.x & 63;
  int row = (blockIdx.x << 2) + wave;
  const float4* xr = (const float4*)(x + (size_t)row * C_);
  float4 v0 = xr[lane], v1 = xr[lane + 64];
  float s = v0.x + v0.y + v0.z + v0.w + v1.x + v1.y + v1.z + v1.w;
  float q = v0.x * v0.x + v0.y * v0.y + v0.z * v0.z + v0.w * v0.w +
            v1.x * v1.x + v1.y * v1.y + v1.z * v1.z + v1.w * v1.w;
#pragma unroll
  for (int off = 32; off; off >>= 1) {
    s += __shfl_xor(s, off);
    q += __shfl_xor(q, off);
  }
  float mean = s * (1.0f / C_);
  float var = q * (1.0f / C_) - mean * mean;
  float rstd = rsqrtf(var + 1e-5f);
  const float4* gr = (const float4*)gam;
  const float4* br = (const float4*)bet;
  float4 g0 = gr[lane], g1 = gr[lane + 64];
  float4 b0 = br[lane], b1 = br[lane + 64];
  u16x4 oa, ob;
  oa.x = f2b((v0.x - mean) * rstd * g0.x + b0.x);
  oa.y = f2b((v0.y - mean) * rstd * g0.y + b0.y);
  oa.z = f2b((v0.z - mean) * rstd * g0.z + b0.z);
  oa.w = f2b((v0.w - mean) * rstd * g0.w + b0.w);
  ob.x = f2b((v1.x - mean) * rstd * g1.x + b1.x);
  ob.y = f2b((v1.y - mean) * rstd * g1.y + b1.y);
  ob.z = f2b((v1.z - mean) * rstd * g1.z + b1.z);
  ob.w = f2b((v1.w - mean) * rstd * g1.w + b1.w);
  unsigned short* yr = y + (size_t)row * C_;
  *(u16x4*)(yr + (lane << 2)) = oa;
  *(u16x4*)(yr + 256 + (lane << 2)) = ob;
}

// ---------------------------------------------------------------------------
// K2: merged prep (weight transposes + frag precomputes).
// ---------------------------------------------------------------------------
__global__ __launch_bounds__(256) void prep_all(
    const float* __restrict__ Wx, const float* __restrict__ Wfx,
    const float* __restrict__ Wout, const float* __restrict__ Wsl,
    const float* __restrict__ Wq, const float* __restrict__ Wk,
    const float* __restrict__ Wv, const float* __restrict__ Wm1,
    const float* __restrict__ Wm2, unsigned short* __restrict__ WtX,
    unsigned short* __restrict__ WtF, unsigned short* __restrict__ WtO,
    unsigned short* __restrict__ wsf, unsigned short* __restrict__ wfr) {
  __shared__ float tile[64][65];
  int blk = blockIdx.x, t = threadIdx.x;
  if (blk < 192) {
    int which = blk >> 6, sub = blk & 63;
    const float* W = (which == 0) ? Wx : (which == 1) ? Wfx : Wout;
    unsigned short* Wt = (which == 0) ? WtX : (which == 1) ? WtF : WtO;
    int r0 = (sub >> 3) << 6, c0 = (sub & 7) << 6;
    int lr = t >> 4, lc = (t & 15) << 2;
#pragma unroll
    for (int p = 0; p < 4; p++) {
      float4 v = *(const float4*)(W + (size_t)(r0 + lr + p * 16) * 512 + c0 + lc);
      tile[lr + p * 16][lc + 0] = v.x;
      tile[lr + p * 16][lc + 1] = v.y;
      tile[lr + p * 16][lc + 2] = v.z;
      tile[lr + p * 16][lc + 3] = v.w;
    }
    __syncthreads();
    int on = t >> 2, ok = (t & 3) << 4;
    unsigned short tmp[16];
#pragma unroll
    for (int j = 0; j < 16; j++) tmp[j] = f2b(tile[ok + j][on]);
    unsigned short* op = Wt + (size_t)(c0 + on) * 512 + r0 + ok;
#pragma unroll
    for (int j4 = 0; j4 < 4; j4++)
      *(u16x4*)(op + (j4 << 2)) = *(u16x4*)(tmp + (j4 << 2));
  } else {
#pragma unroll
    for (int i = 0; i < 2; i++) {
      int idx = t + i * 256;
      int f = idx >> 6, l = idx & 63;
      int gt = f >> 1, ks = f & 1;
      int g = (gt << 4) + (l & 15);
      int d0 = (ks << 5) + ((l >> 4) << 3);
      unsigned short v[8];
#pragma unroll
      for (int jj = 0; jj < 8; jj++) v[jj] = f2b(Wsl[(size_t)(d0 + jj) * 64 + g]);
      *(u16x4*)(wsf + idx * 8) = *(u16x4*)v;
      *(u16x4*)(wsf + idx * 8 + 4) = *(u16x4*)(v + 4);
    }
    for (int task = t; task < 56 * 64; task += 256) {
      int fid = task >> 6, l = task & 63;
      const float* W;
      int stride, ct, ks;
      if (fid < 24) {
        W = (fid < 8) ? Wq : (fid < 16) ? Wk : Wv;
        int e = fid & 7;
        ct = e >> 1;
        ks = e & 1;
        stride = 64;
      } else if (fid < 40) {
        W = Wm1;
        int e = fid - 24;
        ct = e >> 1;
        ks = e & 1;
        stride = 128;
      } else {
        W = Wm2;
        int e = fid - 40;
        ct = e >> 2;
        ks = e & 3;
        stride = 64;
      }
      int d0 = (ks << 5) + ((l >> 4) << 3);
      int c = (ct << 4) + (l & 15);
      unsigned short v[8];
#pragma unroll
      for (int j = 0; j < 8; j++) v[j] = f2b(W[(size_t)(d0 + j) * stride + c]);
      *(u16x4*)(wfr + task * 8) = *(u16x4*)v;
      *(u16x4*)(wfr + task * 8 + 4) = *(u16x4*)(v + 4);
    }
  }
}

// ---------------------------------------------------------------------------
// K4: bf16 MFMA GEMM, single-buffer, BK=64 (unchanged from round 9).
// ---------------------------------------------------------------------------
template <int DEC, bool BIASROW, bool OUTBF, bool RES>
__global__ __launch_bounds__(256) void gemm_bf16(
    const unsigned short* __restrict__ A, const unsigned short* __restrict__ Bt,
    const float* __restrict__ bias, const unsigned short* __restrict__ resid,
    void* __restrict__ Cout, size_t ldC) {
  __shared__ unsigned short lds[16384];
  const int t = threadIdx.x;
  const int w = t >> 6, l = t & 63;
  int bid = blockIdx.x;
  int xcd = bid & 7, q = bid >> 3;
  int bm, bn;
  if (DEC == 0) {
    bm = ((xcd << 5) + (q >> 2)) << 7;
    bn = (q & 3) << 7;
  } else {
    bn = ((xcd << 5) + (q >> 2)) << 7;
    bm = (q & 3) << 7;
  }
  const int wm = (w >> 1) << 6, wn = (w & 1) << 6;
  f32x4 acc[4][4];
#pragma unroll
  for (int mt = 0; mt < 4; mt++)
#pragma unroll
    for (int nt = 0; nt < 4; nt++) acc[mt][nt] = (f32x4){0.f, 0.f, 0.f, 0.f};

  const int srow = t >> 3;
  const int scol = (((t & 7) ^ ((t >> 3) & 7)) << 3);
  const unsigned short* gA = A + (size_t)(bm + srow) * 512 + scol;
  const unsigned short* gB = Bt + (size_t)(bn + srow) * 512 + scol;
  const int fr = l & 15, qq = l >> 4;

  for (int k0 = 0; k0 < 512; k0 += 64) {
#pragma unroll
    for (int i = 0; i < 4; i++)
      gl_lds16(gA + (size_t)(i << 5) * 512 + k0, lds + (i << 11) + (w << 9));
#pragma unroll
    for (int i = 0; i < 4; i++)
      gl_lds16(gB + (size_t)(i << 5) * 512 + k0, lds + 8192 + (i << 11) + (w << 9));
    __syncthreads();
#pragma unroll
    for (int kk = 0; kk < 2; kk++) {
      bf16x8 af[4], bfr[4];
#pragma unroll
      for (int mt = 0; mt < 4; mt++) {
        int row = wm + mt * 16 + fr;
        af[mt] = *(const bf16x8*)&lds[row * 64 + ((((kk << 2) + qq) ^ (fr & 7)) << 3)];
      }
#pragma unroll
      for (int nt = 0; nt < 4; nt++) {
        int row = wn + nt * 16 + fr;
        bfr[nt] = *(const bf16x8*)&lds[8192 + row * 64 + ((((kk << 2) + qq) ^ (fr & 7)) << 3)];
      }
#pragma unroll
      for (int mt = 0; mt < 4; mt++)
#pragma unroll
        for (int nt = 0; nt < 4; nt++)
          acc[mt][nt] = __builtin_amdgcn_mfma_f32_16x16x32_bf16(
              af[mt], bfr[nt], acc[mt][nt], 0, 0, 0);
    }
    __syncthreads();
  }

  const int col0 = bn + wn + (l & 15);
  const int row0 = bm + wm + ((l >> 4) << 2);
#pragma unroll
  for (int mt = 0; mt < 4; mt++) {
#pragma unroll
    for (int j = 0; j < 4; j++) {
      int row = row0 + mt * 16 + j;
#pragma unroll
      for (int nt = 0; nt < 4; nt++) {
        int col = col0 + nt * 16;
        float v = acc[mt][nt][j] + (BIASROW ? bias[row] : bias[col]);
        if (RES) v += b2f(resid[(size_t)row * ldC + col]);
        if (OUTBF)
          ((unsigned short*)Cout)[(size_t)row * ldC + col] = f2b(v);
        else
          ((float*)Cout)[(size_t)row * ldC + col] = v;
      }
    }
  }
}

// ---------------------------------------------------------------------------
// K6: pool + INLINE slice softmax. 1024 blocks (32 chunks of 256 n per bh).
// norm accumulated in registers per lane, shfl-reduced at end.
// ---------------------------------------------------------------------------
__global__ __launch_bounds__(256) void pool_mfma(
    const unsigned short* __restrict__ xmid, const unsigned short* __restrict__ fxT,
    const unsigned short* __restrict__ wf, const float* __restrict__ bslice,
    const float* __restrict__ temp, float* __restrict__ tok_part,
    float* __restrict__ norm_part) {
  __shared__ unsigned short wT[4096];
  __shared__ float wred[4][64];
  int bid = blockIdx.x;
  int bh = bid >> 5, c = bid & 31;
  int b = bh >> 3, h = bh & 7;
  int t = threadIdx.x, w = t >> 6, l = t & 63;
  int n0 = c << 8;
  const int fr15 = l & 15, fs = l >> 4;

  bf16x8 wsf[4][2];
#pragma unroll
  for (int gt = 0; gt < 4; gt++)
#pragma unroll
    for (int ks = 0; ks < 2; ks++)
      wsf[gt][ks] = *(const bf16x8*)(wf + (((gt << 1) + ks) * 64 + l) * 8);
  float invt = 1.0f / temp[h];
  float bsl16[16];
#pragma unroll
  for (int gt = 0; gt < 4; gt++)
#pragma unroll
    for (int r = 0; r < 4; r++)
      bsl16[(gt << 2) + r] = bslice[(gt << 4) + (fs << 2) + r];

  f32x4 acc[4];
#pragma unroll
  for (int gt = 0; gt < 4; gt++) acc[gt] = (f32x4){0.f, 0.f, 0.f, 0.f};
  float nacc[16];
#pragma unroll
  for (int i = 0; i < 16; i++) nacc[i] = 0.f;

  const unsigned short* fxrow =
      fxT + (size_t)(h * 64 + w * 16 + fr15) * 32768 + b * N_ + n0 + (fs << 3);
  const int ncol = (w << 4) + fr15;

  for (int nn = 0; nn < 256; nn += 64) {
    // ---- inline slice: logits + softmax for row (n0+nn+ncol, h) ----
    size_t xrow = ((size_t)(b * N_ + n0 + nn + ncol) * 8 + h) << 6;
    bf16x8 xf0 = *(const bf16x8*)(xmid + xrow + (fs << 3));
    bf16x8 xf1 = *(const bf16x8*)(xmid + xrow + 32 + (fs << 3));
    f32x4 lg4[4];
#pragma unroll
    for (int gt = 0; gt < 4; gt++) {
      lg4[gt] = (f32x4){0.f, 0.f, 0.f, 0.f};
      lg4[gt] = __builtin_amdgcn_mfma_f32_16x16x32_bf16(wsf[gt][0], xf0, lg4[gt], 0, 0, 0);
      lg4[gt] = __builtin_amdgcn_mfma_f32_16x16x32_bf16(wsf[gt][1], xf1, lg4[gt], 0, 0, 0);
    }
    float p[16];
    float mx = -1e30f;
#pragma unroll
    for (int gt = 0; gt < 4; gt++)
#pragma unroll
      for (int r = 0; r < 4; r++) {
        float v = (lg4[gt][r] + bsl16[(gt << 2) + r]) * invt;
        p[(gt << 2) + r] = v;
        mx = fmaxf(mx, v);
      }
    mx = fmaxf(mx, __shfl_xor(mx, 16));
    mx = fmaxf(mx, __shfl_xor(mx, 32));
    float ssum = 0.f;
#pragma unroll
    for (int i = 0; i < 16; i++) {
      p[i] = __expf(p[i] - mx);
      ssum += p[i];
    }
    ssum += __shfl_xor(ssum, 16);
    ssum += __shfl_xor(ssum, 32);
    float inv = 1.0f / ssum;
#pragma unroll
    for (int i = 0; i < 16; i++) {
      p[i] *= inv;
      nacc[i] += p[i];
    }
    __syncthreads();  // prior frag reads done before overwrite
#pragma unroll
    for (int gt = 0; gt < 4; gt++)
#pragma unroll
      for (int r = 0; r < 4; r++) {
        int g = (gt << 4) + (fs << 2) + r;
        wT[(g << 6) + ((((ncol >> 3)) ^ (g & 7)) << 3) + (ncol & 7)] =
            f2b(p[(gt << 2) + r]);
      }
    __syncthreads();
    // ---- pool MFMA ----
#pragma unroll
    for (int kk = 0; kk < 2; kk++) {
      bf16x8 bfrag = *(const bf16x8*)(fxrow + nn + (kk << 5));
#pragma unroll
      for (int gt = 0; gt < 4; gt++) {
        int g = (gt << 4) + fr15;
        int slot = (kk << 2) + fs;
        bf16x8 af = *(const bf16x8*)&wT[(g << 6) + ((slot ^ (g & 7)) << 3)];
        acc[gt] = __builtin_amdgcn_mfma_f32_16x16x32_bf16(af, bfrag, acc[gt], 0, 0, 0);
      }
    }
  }
  float* op = tok_part + ((size_t)bid << 12);
#pragma unroll
  for (int gt = 0; gt < 4; gt++)
#pragma unroll
    for (int rr = 0; rr < 4; rr++)
      op[((gt << 4) + (fs << 2) + rr) * 64 + (w << 4) + fr15] = acc[gt][rr];
  // ---- norm reduce: sum over the wave's 16 rows, then across waves ----
#pragma unroll
  for (int i = 0; i < 16; i++) {
    nacc[i] += __shfl_xor(nacc[i], 1);
    nacc[i] += __shfl_xor(nacc[i], 2);
    nacc[i] += __shfl_xor(nacc[i], 4);
    nacc[i] += __shfl_xor(nacc[i], 8);
  }
  if (fr15 == 0) {
#pragma unroll
    for (int i = 0; i < 16; i++)
      wred[w][((i >> 2) << 4) + (fs << 2) + (i & 3)] = nacc[i];
  }
  __syncthreads();
  if (t < 64)
    norm_part[((size_t)bid << 6) + t] =
        wred[0][t] + wred[1][t] + wred[2][t] + wred[3][t];
}

// ---------------------------------------------------------------------------
// K7: token pipeline via MFMA + fused tok_part reduce + deslice-frag emit.
// ---------------------------------------------------------------------------
__device__ __forceinline__ float gelu_exact(float x) {
  return 0.5f * x * (1.0f + erff(x * 0.70710678118654752f));
}

__global__ __launch_bounds__(256) void token_mfma(
    const float* __restrict__ tok_part, const float* __restrict__ norm_part,
    const unsigned short* __restrict__ wfr, const float* __restrict__ tg,
    const float* __restrict__ tb, const float* __restrict__ bm1,
    const float* __restrict__ bm2, unsigned short* __restrict__ wtokf) {
  __shared__ __align__(16) char smem[54272];
  __shared__ float red[64];
  unsigned short* stb = (unsigned short*)smem;
  float* st32 = (float*)(smem + 9216);
  unsigned short* hmld = (unsigned short*)(smem + 9216);
  unsigned short* qld = (unsigned short*)(smem + 26624);
  unsigned short* kld = (unsigned short*)(smem + 35840);
  unsigned short* vtl = (unsigned short*)(smem + 45056);

  int bh = blockIdx.x, t = threadIdx.x, w = t >> 6, l = t & 63;
  const int fr = l & 15, fq = l >> 4;

  // ---- fused reduce of tok_part + norm_part -> slice_tok ----
  if (t < 64) {
    float s = 0.f;
    const float* np = norm_part + ((size_t)bh << 11);
#pragma unroll
    for (int cc = 0; cc < 32; cc++) s += np[(cc << 6) + t];
    red[t] = s;
  }
  {
    float a16[16];
#pragma unroll
    for (int j = 0; j < 16; j++) a16[j] = 0.f;
    const float* tp = tok_part + ((size_t)bh << 17) + (t << 4);
    for (int cc = 0; cc < 32; cc++) {
      const float* pp = tp + (cc << 12);
#pragma unroll
      for (int j4 = 0; j4 < 4; j4++) {
        float4 v = *(const float4*)(pp + (j4 << 2));
        a16[j4 * 4 + 0] += v.x;
        a16[j4 * 4 + 1] += v.y;
        a16[j4 * 4 + 2] += v.z;
        a16[j4 * 4 + 3] += v.w;
      }
    }
    __syncthreads();
    float rn = 1.0f / (red[t >> 2] + 1e-5f);
    int r = t >> 2, c0 = (t & 3) << 4;
    unsigned short tv[16];
#pragma unroll
    for (int j = 0; j < 16; j++) {
      float v = a16[j] * rn;
      st32[r * 68 + c0 + j] = v;
      tv[j] = f2b(v);
    }
    *(u16x8*)&stb[r * 72 + c0] = *(u16x8*)tv;
    *(u16x8*)&stb[r * 72 + c0 + 8] = *(u16x8*)(tv + 8);
  }
  __syncthreads();

  const int orow = (w << 4) + (fq << 2);

  {
    bf16x8 af[2];
#pragma unroll
    for (int ks = 0; ks < 2; ks++)
      af[ks] = *(const bf16x8*)&stb[((w << 4) + fr) * 72 + (ks << 5) + (fq << 3)];
    f32x4 aq[4], ak[4], av[4];
#pragma unroll
    for (int ct = 0; ct < 4; ct++) {
      aq[ct] = (f32x4){0.f, 0.f, 0.f, 0.f};
      ak[ct] = (f32x4){0.f, 0.f, 0.f, 0.f};
      av[ct] = (f32x4){0.f, 0.f, 0.f, 0.f};
    }
#pragma unroll
    for (int ct = 0; ct < 4; ct++)
#pragma unroll
      for (int ks = 0; ks < 2; ks++) {
        bf16x8 bq = *(const bf16x8*)&wfr[(((ct << 1) + ks) * 64 + l) * 8];
        aq[ct] = __builtin_amdgcn_mfma_f32_16x16x32_bf16(af[ks], bq, aq[ct], 0, 0, 0);
      }
#pragma unroll
    for (int ct = 0; ct < 4; ct++)
#pragma unroll
      for (int ks = 0; ks < 2; ks++) {
        bf16x8 bk = *(const bf16x8*)&wfr[((8 + (ct << 1) + ks) * 64 + l) * 8];
        ak[ct] = __builtin_amdgcn_mfma_f32_16x16x32_bf16(af[ks], bk, ak[ct], 0, 0, 0);
      }
#pragma unroll
    for (int ct = 0; ct < 4; ct++)
#pragma unroll
      for (int ks = 0; ks < 2; ks++) {
        bf16x8 bv = *(const bf16x8*)&wfr[((16 + (ct << 1) + ks) * 64 + l) * 8];
        av[ct] = __builtin_amdgcn_mfma_f32_16x16x32_bf16(af[ks], bv, av[ct], 0, 0, 0);
      }
#pragma unroll
    for (int ct = 0; ct < 4; ct++) {
#pragma unroll
      for (int rr = 0; rr < 4; rr++) {
        qld[(orow + rr) * 72 + (ct << 4) + fr] = f2b(aq[ct][rr]);
        kld[(orow + rr) * 72 + (ct << 4) + fr] = f2b(ak[ct][rr]);
      }
      u16x4 vp;
      vp.x = f2b(av[ct][0]);
      vp.y = f2b(av[ct][1]);
      vp.z = f2b(av[ct][2]);
      vp.w = f2b(av[ct][3]);
      *(u16x4*)&vtl[((ct << 4) + fr) * 72 + orow] = vp;
    }
  }
  __syncthreads();

  {
    bf16x8 aq[2];
#pragma unroll
    for (int ks = 0; ks < 2; ks++)
      aq[ks] = *(const bf16x8*)&qld[((w << 4) + fr) * 72 + (ks << 5) + (fq << 3)];
    f32x4 accs[4];
#pragma unroll
    for (int nt = 0; nt < 4; nt++) accs[nt] = (f32x4){0.f, 0.f, 0.f, 0.f};
#pragma unroll
    for (int nt = 0; nt < 4; nt++)
#pragma unroll
      for (int ks = 0; ks < 2; ks++) {
        bf16x8 bk = *(const bf16x8*)&kld[((nt << 4) + fr) * 72 + (ks << 5) + (fq << 3)];
        accs[nt] = __builtin_amdgcn_mfma_f32_16x16x32_bf16(aq[ks], bk, accs[nt], 0, 0, 0);
      }
#pragma unroll
    for (int rr = 0; rr < 4; rr++) {
      float v0 = accs[0][rr] * 0.125f, v1 = accs[1][rr] * 0.125f;
      float v2 = accs[2][rr] * 0.125f, v3 = accs[3][rr] * 0.125f;
      float mx = fmaxf(fmaxf(v0, v1), fmaxf(v2, v3));
      mx = fmaxf(mx, __shfl_xor(mx, 1));
      mx = fmaxf(mx, __shfl_xor(mx, 2));
      mx = fmaxf(mx, __shfl_xor(mx, 4));
      mx = fmaxf(mx, __shfl_xor(mx, 8));
      float e0 = __expf(v0 - mx), e1 = __expf(v1 - mx);
      float e2 = __expf(v2 - mx), e3 = __expf(v3 - mx);
      float ss = e0 + e1 + e2 + e3;
      ss += __shfl_xor(ss, 1);
      ss += __shfl_xor(ss, 2);
      ss += __shfl_xor(ss, 4);
      ss += __shfl_xor(ss, 8);
      float inv = 1.0f / ss;
      stb[(orow + rr) * 72 + 0 * 16 + fr] = f2b(e0 * inv);
      stb[(orow + rr) * 72 + 1 * 16 + fr] = f2b(e1 * inv);
      stb[(orow + rr) * 72 + 2 * 16 + fr] = f2b(e2 * inv);
      stb[(orow + rr) * 72 + 3 * 16 + fr] = f2b(e3 * inv);
    }
  }
  __syncthreads();

  float o16[4][4];
  {
    bf16x8 ap[2];
#pragma unroll
    for (int ks = 0; ks < 2; ks++)
      ap[ks] = *(const bf16x8*)&stb[((w << 4) + fr) * 72 + (ks << 5) + (fq << 3)];
    f32x4 acco[4];
#pragma unroll
    for (int ct = 0; ct < 4; ct++) acco[ct] = (f32x4){0.f, 0.f, 0.f, 0.f};
#pragma unroll
    for (int ct = 0; ct < 4; ct++)
#pragma unroll
      for (int ks = 0; ks < 2; ks++) {
        bf16x8 bv = *(const bf16x8*)&vtl[((ct << 4) + fr) * 72 + (ks << 5) + (fq << 3)];
        acco[ct] = __builtin_amdgcn_mfma_f32_16x16x32_bf16(ap[ks], bv, acco[ct], 0, 0, 0);
      }
    float tgv[4], tbv[4];
#pragma unroll
    for (int ct = 0; ct < 4; ct++) {
      tgv[ct] = tg[(ct << 4) + fr];
      tbv[ct] = tb[(ct << 4) + fr];
    }
#pragma unroll
    for (int ct = 0; ct < 4; ct++)
#pragma unroll
      for (int rr = 0; rr < 4; rr++)
        o16[ct][rr] = acco[ct][rr] + st32[(orow + rr) * 68 + (ct << 4) + fr];
#pragma unroll
    for (int rr = 0; rr < 4; rr++) {
      float sm = o16[0][rr] + o16[1][rr] + o16[2][rr] + o16[3][rr];
      float sq = o16[0][rr] * o16[0][rr] + o16[1][rr] * o16[1][rr] +
                 o16[2][rr] * o16[2][rr] + o16[3][rr] * o16[3][rr];
      sm += __shfl_xor(sm, 1);
      sm += __shfl_xor(sm, 2);
      sm += __shfl_xor(sm, 4);
      sm += __shfl_xor(sm, 8);
      sq += __shfl_xor(sq, 1);
      sq += __shfl_xor(sq, 2);
      sq += __shfl_xor(sq, 4);
      sq += __shfl_xor(sq, 8);
      float mean = sm * (1.0f / 64.0f);
      float var = sq * (1.0f / 64.0f) - mean * mean;
      float rstd = rsqrtf(var + 1e-5f);
#pragma unroll
      for (int ct = 0; ct < 4; ct++) {
        float hv = (o16[ct][rr] - mean) * rstd * tgv[ct] + tbv[ct];
        qld[(orow + rr) * 72 + (ct << 4) + fr] = f2b(hv);
      }
    }
  }
  __syncthreads();

  {
    bf16x8 ah[2];
#pragma unroll
    for (int ks = 0; ks < 2; ks++)
      ah[ks] = *(const bf16x8*)&qld[((w << 4) + fr) * 72 + (ks << 5) + (fq << 3)];
    f32x4 accm[8];
#pragma unroll
    for (int et = 0; et < 8; et++) accm[et] = (f32x4){0.f, 0.f, 0.f, 0.f};
#pragma unroll
    for (int et = 0; et < 8; et++)
#pragma unroll
      for (int ks = 0; ks < 2; ks++) {
        bf16x8 bm = *(const bf16x8*)&wfr[((24 + (et << 1) + ks) * 64 + l) * 8];
        accm[et] = __builtin_amdgcn_mfma_f32_16x16x32_bf16(ah[ks], bm, accm[et], 0, 0, 0);
      }
#pragma unroll
    for (int et = 0; et < 8; et++) {
      float bv = bm1[(et << 4) + fr];
#pragma unroll
      for (int rr = 0; rr < 4; rr++) {
        float x = accm[et][rr] + bv;
        hmld[(orow + rr) * 136 + (et << 4) + fr] = f2b(gelu_exact(x));
      }
    }
  }
  __syncthreads();

  {
    bf16x8 ahm[4];
#pragma unroll
    for (int ks = 0; ks < 4; ks++)
      ahm[ks] = *(const bf16x8*)&hmld[((w << 4) + fr) * 136 + (ks << 5) + (fq << 3)];
    f32x4 acc2[4];
#pragma unroll
    for (int ct = 0; ct < 4; ct++) acc2[ct] = (f32x4){0.f, 0.f, 0.f, 0.f};
#pragma unroll
    for (int ct = 0; ct < 4; ct++)
#pragma unroll
      for (int ks = 0; ks < 4; ks++) {
        bf16x8 bw = *(const bf16x8*)&wfr[((40 + (ct << 2) + ks) * 64 + l) * 8];
        acc2[ct] = __builtin_amdgcn_mfma_f32_16x16x32_bf16(ahm[ks], bw, acc2[ct], 0, 0, 0);
      }
#pragma unroll
    for (int ct = 0; ct < 4; ct++) {
      float bv = bm2[(ct << 4) + fr];
#pragma unroll
      for (int rr = 0; rr < 4; rr++)
        stb[(orow + rr) * 72 + (ct << 4) + fr] =
            f2b(acc2[ct][rr] + bv + o16[ct][rr]);
    }
  }
  __syncthreads();
  {
#pragma unroll
    for (int e = 0; e < 2; e++) {
      int fid = (w << 1) + e;
      int d = (w << 4) + (l & 15);
      int g0 = (e << 5) + ((l >> 4) << 3);
      unsigned short v[8];
#pragma unroll
      for (int j = 0; j < 8; j++) v[j] = stb[(g0 + j) * 72 + d];
      unsigned short* op = wtokf + (((size_t)bh << 3) + fid) * 512 + (l << 3);
      *(u16x4*)op = *(u16x4*)v;
      *(u16x4*)(op + 4) = *(u16x4*)(v + 4);
    }
  }
}

// ---------------------------------------------------------------------------
// K8: deslice + INLINE slice softmax. 1024 blocks (32 chunks of 256 n).
// ---------------------------------------------------------------------------
__global__ __launch_bounds__(256) void deslice_mfma(
    const unsigned short* __restrict__ wtokf, const unsigned short* __restrict__ xmid,
    const unsigned short* __restrict__ wf, const float* __restrict__ bslice,
    const float* __restrict__ temp, unsigned short* __restrict__ outx) {
  __shared__ unsigned short pex[4][1024];
  int bid = blockIdx.x;
  int bh = bid >> 5, c = bid & 31;
  int b = bh >> 3, h = bh & 7;
  int t = threadIdx.x, w = t >> 6, l = t & 63;
  const int fr = l & 15, fq = l >> 4;
  unsigned short* pw = pex[w];

  bf16x8 ta[4][2];
  const unsigned short* fp = wtokf + ((size_t)bh << 12);
#pragma unroll
  for (int mt = 0; mt < 4; mt++)
#pragma unroll
    for (int ks = 0; ks < 2; ks++)
      ta[mt][ks] = *(const bf16x8*)(fp + (((mt << 1) + ks) << 9) + (l << 3));
  bf16x8 wsf[4][2];
#pragma unroll
  for (int gt = 0; gt < 4; gt++)
#pragma unroll
    for (int ks = 0; ks < 2; ks++)
      wsf[gt][ks] = *(const bf16x8*)(wf + (((gt << 1) + ks) * 64 + l) * 8);
  float invt = 1.0f / temp[h];
  float bsl16[16];
#pragma unroll
  for (int gt = 0; gt < 4; gt++)
#pragma unroll
    for (int r = 0; r < 4; r++)
      bsl16[(gt << 2) + r] = bslice[(gt << 4) + (fq << 2) + r];

  int n0 = (c << 8) + (w << 6);
#pragma unroll
  for (int ntile = 0; ntile < 4; ntile++) {
    int nb = n0 + (ntile << 4);
    size_t rowb = ((size_t)(b * N_ + nb + fr) * 8 + h) << 6;
    bf16x8 xf0 = *(const bf16x8*)(xmid + rowb + (fq << 3));
    bf16x8 xf1 = *(const bf16x8*)(xmid + rowb + 32 + (fq << 3));
    f32x4 lg4[4];
#pragma unroll
    for (int gt = 0; gt < 4; gt++) {
      lg4[gt] = (f32x4){0.f, 0.f, 0.f, 0.f};
      lg4[gt] = __builtin_amdgcn_mfma_f32_16x16x32_bf16(wsf[gt][0], xf0, lg4[gt], 0, 0, 0);
      lg4[gt] = __builtin_amdgcn_mfma_f32_16x16x32_bf16(wsf[gt][1], xf1, lg4[gt], 0, 0, 0);
    }
    float p[16];
    float mx = -1e30f;
#pragma unroll
    for (int gt = 0; gt < 4; gt++)
#pragma unroll
      for (int r = 0; r < 4; r++) {
        float v = (lg4[gt][r] + bsl16[(gt << 2) + r]) * invt;
        p[(gt << 2) + r] = v;
        mx = fmaxf(mx, v);
      }
    mx = fmaxf(mx, __shfl_xor(mx, 16));
    mx = fmaxf(mx, __shfl_xor(mx, 32));
    float ssum = 0.f;
#pragma unroll
    for (int i = 0; i < 16; i++) {
      p[i] = __expf(p[i] - mx);
      ssum += p[i];
    }
    ssum += __shfl_xor(ssum, 16);
    ssum += __shfl_xor(ssum, 32);
    float inv = 1.0f / ssum;
#pragma unroll
    for (int gt = 0; gt < 4; gt++)
#pragma unroll
      for (int r = 0; r < 4; r++) {
        int g = (gt << 4) + (fq << 2) + r;
        pw[(fr << 6) + (((g >> 3) ^ (fr & 7)) << 3) + (g & 7)] =
            f2b(p[(gt << 2) + r] * inv);
      }
    bf16x8 b0 = *(const bf16x8*)&pw[(fr << 6) + ((fq ^ (fr & 7)) << 3)];
    bf16x8 b1 = *(const bf16x8*)&pw[(fr << 6) + (((4 + fq) ^ (fr & 7)) << 3)];
    f32x4 acc[4];
#pragma unroll
    for (int mt = 0; mt < 4; mt++) acc[mt] = (f32x4){0.f, 0.f, 0.f, 0.f};
#pragma unroll
    for (int mt = 0; mt < 4; mt++) {
      acc[mt] = __builtin_amdgcn_mfma_f32_16x16x32_bf16(ta[mt][0], b0, acc[mt], 0, 0, 0);
      acc[mt] = __builtin_amdgcn_mfma_f32_16x16x32_bf16(ta[mt][1], b1, acc[mt], 0, 0, 0);
    }
    unsigned short* op = outx + rowb + (fq << 2);
#pragma unroll
    for (int mt = 0; mt < 4; mt++) {
      u16x4 pk;
      pk.x = f2b(acc[mt][0]);
      pk.y = f2b(acc[mt][1]);
      pk.z = f2b(acc[mt][2]);
      pk.w = f2b(acc[mt][3]);
      *(u16x4*)(op + (mt << 4)) = pk;
    }
  }
}

// ---------------------------------------------------------------------------
extern "C" void kernel_launch(void* const* d_in, const int* in_sizes, int n_in,
                              void* d_out, int out_size, void* d_ws,
                              size_t ws_size, hipStream_t stream) {
  const float* fx = (const float*)d_in[0];
  const float* ln1g = (const float*)d_in[1];
  const float* ln1b = (const float*)d_in[2];
  const float* Wx = (const float*)d_in[3];
  const float* bx = (const float*)d_in[4];
  const float* Wfx = (const float*)d_in[5];
  const float* bfx = (const float*)d_in[6];
  const float* Wsl = (const float*)d_in[7];
  const float* bsl = (const float*)d_in[8];
  const float* temp = (const float*)d_in[9];
  const float* Wq = (const float*)d_in[10];
  const float* Wk = (const float*)d_in[11];
  const float* Wv = (const float*)d_in[12];
  const float* Wout = (const float*)d_in[13];
  const float* bout = (const float*)d_in[14];
  const float* tlng = (const float*)d_in[15];
  const float* tlnb = (const float*)d_in[16];
  const float* Wm1 = (const float*)d_in[17];
  const float* bm1 = (const float*)d_in[18];
  const float* Wm2 = (const float*)d_in[19];
  const float* bm2 = (const float*)d_in[20];
  float* out = (float*)d_out;

  char* p = (char*)d_ws;
  const size_t MC2 = (size_t)M_ * 512 * 2;
  unsigned short* fxn = (unsigned short*)p;  p += MC2;
  unsigned short* buf1 = (unsigned short*)p; p += MC2;  // x_mid
  unsigned short* bufT = (unsigned short*)p; p += MC2;  // fxT -> out_x
  unsigned short* WtX = (unsigned short*)p;  p += 512 * 512 * 2;
  unsigned short* WtF = (unsigned short*)p;  p += 512 * 512 * 2;
  unsigned short* WtO = (unsigned short*)p;  p += 512 * 512 * 2;
  unsigned short* wsf = (unsigned short*)p;  p += 8192;
  unsigned short* wfr = (unsigned short*)p;  p += 56 * 512 * 2;
  unsigned short* wtokf = (unsigned short*)p; p += (size_t)32 * 8 * 512 * 2;
  float* tok_part = (float*)p;  p += (size_t)1024 * 4096 * 4;
  float* norm_part = (float*)p; p += (size_t)1024 * 64 * 4;

  ln_bf16<<<M_ / 4, 256, 0, stream>>>(fx, ln1g, ln1b, fxn);
  prep_all<<<193, 256, 0, stream>>>(Wx, Wfx, Wout, Wsl, Wq, Wk, Wv, Wm1, Wm2,
                                    WtX, WtF, WtO, wsf, wfr);
  gemm_bf16<0, false, true, false><<<1024, 256, 0, stream>>>(fxn, WtX, bx, nullptr, buf1, 512);
  gemm_bf16<1, true, true, false><<<1024, 256, 0, stream>>>(WtF, fxn, bfx, nullptr, bufT, 32768);
  pool_mfma<<<1024, 256, 0, stream>>>(buf1, bufT, wsf, bsl, temp, tok_part, norm_part);
  token_mfma<<<32, 256, 0, stream>>>(tok_part, norm_part, wfr, tlng, tlnb, bm1, bm2, wtokf);
  deslice_mfma<<<1024, 256, 0, stream>>>(wtokf, buf1, wsf, bsl, temp, bufT);
  gemm_bf16<0, false, false, true><<<1024, 256, 0, stream>>>(bufT, WtO, bout, fxn, out, 512);
}